// Round 6
// baseline (517.379 us; speedup 1.0000x reference)
//
#include <hip/hip_runtime.h>
#include <hip/hip_bf16.h>
#include <math.h>

#define N_ROWS   131072   // 8*16384
#define DIMS     64
#define NCODES   1024
#define DECAY    0.99f
#define EPSF     1e-5f

// d_out layout (float32 elements)
#define OFF_ZQ    0
#define OFF_IDX   8388608
#define OFF_LOSS  8519680
#define OFF_PERP  8519681
#define OFF_EMB   8519682
#define OFF_ECS   8585218
#define OFF_EMAW  8586242

typedef unsigned int uint;

__device__ __forceinline__ double atomic_add_f64(double* p, double v) {
  return __hip_atomic_fetch_add(p, v, __ATOMIC_RELAXED, __HIP_MEMORY_SCOPE_AGENT);
}

// numpy pairwise_sum base case (8 <= n <= 128), n = 64: 8 strided accumulators,
// tree combine. Inputs are the already-rounded f32 products.
__device__ __forceinline__ float np_pairwise64_sq(const float* v) {
#pragma clang fp contract(off)
  float r[8];
#pragma unroll
  for (int j = 0; j < 8; ++j) r[j] = v[j] * v[j];
#pragma unroll
  for (int i = 8; i < 64; i += 8)
#pragma unroll
    for (int j = 0; j < 8; ++j) r[j] += v[i + j] * v[i + j];
  return ((r[0] + r[1]) + (r[2] + r[3])) + ((r[4] + r[5]) + (r[6] + r[7]));
}

// ---------------- K0: init ws + np-exact code norms ----------------
__global__ __launch_bounds__(256) void k0_init(const float* __restrict__ emb,
                                               float* __restrict__ ee,
                                               uint* __restrict__ cluster,
                                               double* __restrict__ sq) {
  int gid = blockIdx.x * 256 + threadIdx.x;   // grid 4 -> 1024 threads
  if (gid < NCODES) {
    cluster[gid] = 0u;
    float ev[DIMS];
    const float4* e4 = (const float4*)(emb + (size_t)gid * DIMS);
#pragma unroll
    for (int i = 0; i < 16; ++i) {
      float4 v = e4[i];
      ev[4*i] = v.x; ev[4*i+1] = v.y; ev[4*i+2] = v.z; ev[4*i+3] = v.w;
    }
    ee[gid] = np_pairwise64_sq(ev);
  }
  if (gid == 0) { *sq = 0.0; }
}

// ---------------- K1: numpy-f32-bit-exact argmin --------------------------
// Block = 256 thr = 4 waves over 64 rows (lane = row); wave w scans codes
// [256w, 256w+256). z rows live in LDS (XOR-swizzled, slot = j ^ (row&15),
// bijective per row; kills the 32-way stride-256B bank conflict) and are
// re-read per 4-code group -> tiny register footprint, no AGPR round-trips
// (rounds 2-5: 2.35x VALU bloat from the allocator shuffling the 64-float
// z row through AGPRs).
// Per-code math identical to numpy-f32 (validated rounds 2-5):
//   d[c] = fl( fl(zz + ee[c]) - 2*dot_c ), dot_c = sequential single-acc FMA,
//   zz = numpy pairwise square-sum. Strict < ascending c = first-index argmin.
#define FMA4(ZC, K) \
  a0 = fmaf(ZC, e0[K], a0); a1 = fmaf(ZC, e1[K], a1); \
  a2 = fmaf(ZC, e2[K], a2); a3 = fmaf(ZC, e3[K], a3);

// sequential 8-term strided square-sum chain (numpy accumulator j)
#define SQ8(A,B,C,D,E,F,G,H) \
  (((((((A*A + B*B) + C*C) + D*D) + E*E) + F*F) + G*G) + H*H)

__global__ __launch_bounds__(256, 4) void k1_exact(const float* __restrict__ z,
                                                   const float* __restrict__ emb,
                                                   const float* __restrict__ ee,
                                                   int* __restrict__ idx_out,
                                                   float* __restrict__ idx_f_out) {
#pragma clang fp contract(off)
  __shared__ float zbuf[64 * DIMS];
  __shared__ float sval[4][64];
  __shared__ int   sidx[4][64];
  float4* zt = (float4*)zbuf;

  int t = threadIdx.x;
  int lane = t & 63;
  int chunk = __builtin_amdgcn_readfirstlane(t >> 6);

  // stage 64 rows: coalesced global read, swizzled LDS write
  const float4* zg = (const float4*)(z + (size_t)blockIdx.x * 64 * DIMS);
#pragma unroll
  for (int p = 0; p < 4; ++p) {
    int f = t + p * 256;               // 1024 float4s
    int row = f >> 4, j = f & 15;
    zt[row * 16 + (j ^ (row & 15))] = zg[f];
  }
  __syncthreads();

  // per-lane swizzled slot table (static indices after unroll -> registers)
  int zo[16];
#pragma unroll
  for (int j = 0; j < 16; ++j) zo[j] = lane * 16 + (j ^ (lane & 15));

  // zz in numpy pairwise order (bits identical to rounds 2-5)
  float4 ze0 = zt[zo[0]],  ze1 = zt[zo[2]],  ze2 = zt[zo[4]],  ze3 = zt[zo[6]];
  float4 ze4 = zt[zo[8]],  ze5 = zt[zo[10]], ze6 = zt[zo[12]], ze7 = zt[zo[14]];
  float r0 = SQ8(ze0.x, ze1.x, ze2.x, ze3.x, ze4.x, ze5.x, ze6.x, ze7.x);
  float r1 = SQ8(ze0.y, ze1.y, ze2.y, ze3.y, ze4.y, ze5.y, ze6.y, ze7.y);
  float r2 = SQ8(ze0.z, ze1.z, ze2.z, ze3.z, ze4.z, ze5.z, ze6.z, ze7.z);
  float r3 = SQ8(ze0.w, ze1.w, ze2.w, ze3.w, ze4.w, ze5.w, ze6.w, ze7.w);
  float4 zd0 = zt[zo[1]],  zd1 = zt[zo[3]],  zd2 = zt[zo[5]],  zd3 = zt[zo[7]];
  float4 zd4 = zt[zo[9]],  zd5 = zt[zo[11]], zd6 = zt[zo[13]], zd7 = zt[zo[15]];
  float r4 = SQ8(zd0.x, zd1.x, zd2.x, zd3.x, zd4.x, zd5.x, zd6.x, zd7.x);
  float r5 = SQ8(zd0.y, zd1.y, zd2.y, zd3.y, zd4.y, zd5.y, zd6.y, zd7.y);
  float r6 = SQ8(zd0.z, zd1.z, zd2.z, zd3.z, zd4.z, zd5.z, zd6.z, zd7.z);
  float r7 = SQ8(zd0.w, zd1.w, zd2.w, zd3.w, zd4.w, zd5.w, zd6.w, zd7.w);
  float zz = ((r0 + r1) + (r2 + r3)) + ((r4 + r5) + (r6 + r7));

  float best = 3.4e38f;
  int bidx = 0;
  int cbase = chunk * 256;

  for (int cc = 0; cc < 256; cc += 4) {
    int c0 = cbase + cc;
    const float* e0 = emb + (size_t)c0 * DIMS;   // wave-uniform -> s_load
    const float* e1 = e0 + DIMS;
    const float* e2 = e0 + 2 * DIMS;
    const float* e3 = e0 + 3 * DIMS;
    float a0 = 0.f, a1 = 0.f, a2 = 0.f, a3 = 0.f;
#pragma unroll
    for (int j = 0; j < 16; ++j) {
      float4 zk = zt[zo[j]];                      // one ds_read_b128 / 16 FMA
      FMA4(zk.x, 4*j)   FMA4(zk.y, 4*j+1)
      FMA4(zk.z, 4*j+2) FMA4(zk.w, 4*j+3)
    }
    float t0 = zz + ee[c0];
    float t1 = zz + ee[c0 + 1];
    float t2 = zz + ee[c0 + 2];
    float t3 = zz + ee[c0 + 3];
    float d0 = fmaf(-2.0f, a0, t0);  // fl(t - 2*dot): one rounding, == numpy
    float d1 = fmaf(-2.0f, a1, t1);
    float d2 = fmaf(-2.0f, a2, t2);
    float d3 = fmaf(-2.0f, a3, t3);
    if (d0 < best) { best = d0; bidx = c0; }
    if (d1 < best) { best = d1; bidx = c0 + 1; }
    if (d2 < best) { best = d2; bidx = c0 + 2; }
    if (d3 < best) { best = d3; bidx = c0 + 3; }
  }

  sval[chunk][lane] = best;
  sidx[chunk][lane] = bidx;
  __syncthreads();
  if (t < 64) {
    float bv = sval[0][t];
    int   bi = sidx[0][t];
#pragma unroll
    for (int w = 1; w < 4; ++w) {
      float v = sval[w][t];             // ascending chunk, strict < keeps
      int   i = sidx[w][t];             // lowest index on exact ties
      if (v < bv) { bv = v; bi = i; }
    }
    int orow = blockIdx.x * 64 + t;
    idx_out[orow] = bi;
    idx_f_out[orow] = (float)bi;
  }
}

// ---------------- K3a: zq write, loss accum, cluster counts ----------------
__global__ __launch_bounds__(256) void k3a_gather(const float* __restrict__ z,
                                                  const float* __restrict__ emb,
                                                  const int* __restrict__ idx,
                                                  float* __restrict__ out_zq,
                                                  uint* __restrict__ cluster,
                                                  double* __restrict__ sq) {
  int gid = blockIdx.x * 256 + threadIdx.x;   // over N_ROWS*16 float4s
  int row = gid >> 4, d4 = gid & 15;
  int code = idx[row];

  float4 zv = ((const float4*)z)[gid];
  float4 ev = ((const float4*)emb)[code * 16 + d4];

  // z_q_st = z + (z_q - z), replicated op-for-op
  float dx = ev.x - zv.x, dy = ev.y - zv.y, dz = ev.z - zv.z, dw_ = ev.w - zv.w;
  float4 o;
  o.x = zv.x + dx; o.y = zv.y + dy; o.z = zv.z + dz; o.w = zv.w + dw_;
  ((float4*)out_zq)[gid] = o;

  float ss = dx * dx + dy * dy + dz * dz + dw_ * dw_;

  if (d4 == 0) atomicAdd(&cluster[code], 1u);

  // block-reduce ss -> one f64 atomic per block
  double bs = (double)ss;
#pragma unroll
  for (int o2 = 32; o2 > 0; o2 >>= 1) bs += __shfl_down(bs, o2, 64);
  __shared__ double wsum[4];
  int lane = threadIdx.x & 63, wid = threadIdx.x >> 6;
  if (lane == 0) wsum[wid] = bs;
  __syncthreads();
  if (threadIdx.x == 0) {
    double tt = (wsum[0] + wsum[1]) + (wsum[2] + wsum[3]);
    atomic_add_f64(sq, tt);
  }
}

// ---------------- K3b: exclusive prefix over counts (1 block) --------------
__global__ __launch_bounds__(256) void k3b_prefix(const uint* __restrict__ cluster,
                                                  uint* __restrict__ starts,
                                                  uint* __restrict__ cursor) {
  __shared__ uint a[256], b[256];
  int t = threadIdx.x;
  uint c0 = cluster[t*4+0], c1 = cluster[t*4+1], c2 = cluster[t*4+2], c3 = cluster[t*4+3];
  uint s = c0 + c1 + c2 + c3;
  a[t] = s;
  __syncthreads();
  uint* src = a; uint* dst = b;
  for (int off = 1; off < 256; off <<= 1) {
    dst[t] = src[t] + ((t >= off) ? src[t - off] : 0u);
    __syncthreads();
    uint* tmp = src; src = dst; dst = tmp;
  }
  uint base = (t > 0) ? src[t-1] : 0u;   // exclusive prefix of 4-chunks
  uint p0 = base, p1 = p0 + c0, p2 = p1 + c1, p3 = p2 + c2;
  starts[t*4+0] = p0; starts[t*4+1] = p1; starts[t*4+2] = p2; starts[t*4+3] = p3;
  cursor[t*4+0] = p0; cursor[t*4+1] = p1; cursor[t*4+2] = p2; cursor[t*4+3] = p3;
  if (t == 255) starts[NCODES] = src[255];
}

// ---------------- K3c: scatter row ids into code buckets -------------------
__global__ __launch_bounds__(256) void k3c_scatter(const int* __restrict__ idx,
                                                   uint* __restrict__ cursor,
                                                   uint* __restrict__ rowids) {
  int row = blockIdx.x * 256 + threadIdx.x;
  int code = idx[row];
  uint pos = atomicAdd(&cursor[code], 1u);
  rowids[pos] = (uint)row;
}

// ---------------- K3d: per-code segmented sum (block per code) -------------
__global__ __launch_bounds__(256) void k3d_sum(const float* __restrict__ z,
                                               const uint* __restrict__ starts,
                                               const uint* __restrict__ rowids,
                                               float* __restrict__ dw) {
  __shared__ float acc[4][64];
  int code = blockIdx.x;
  int lane = threadIdx.x & 63, w = threadIdx.x >> 6;
  uint s0 = starts[code], s1 = starts[code + 1];
  float s = 0.f;
  for (uint i = s0 + (uint)w; i < s1; i += 4) {
    uint r = rowids[i];                       // wave-uniform -> s_load
    s += z[(size_t)r * DIMS + lane];          // 64-lane coalesced 256B
  }
  acc[w][lane] = s;
  __syncthreads();
  if (threadIdx.x < 64) {
    float v = (acc[0][threadIdx.x] + acc[1][threadIdx.x])
            + (acc[2][threadIdx.x] + acc[3][threadIdx.x]);
    dw[code * DIMS + threadIdx.x] = v;        // every element written: no zeroing
  }
}

// ---------------- K4a: serial finalize (1 block): ecs, n, loss, perp, cs ----
__global__ __launch_bounds__(256) void k4a_scalar(const float* __restrict__ ecs_in,
                                                  const uint* __restrict__ cluster,
                                                  const double* __restrict__ sq,
                                                  float* __restrict__ csb,
                                                  float* __restrict__ out) {
  __shared__ double red[256];
  int t = threadIdx.x;

  double nloc = 0.0, aloc = 0.0, bloc = 0.0;
  for (int c = t; c < NCODES; c += 256) {
    float cntf = (float)cluster[c];
    float ne = ecs_in[c] * DECAY + (1.0f - DECAY) * cntf;
    out[OFF_ECS + c] = ne;
    nloc += (double)ne;
    double p = (double)cntf / (double)N_ROWS;
    double pc = p < 1e-10 ? 1e-10 : p;
    bloc += pc;
    aloc += pc * log(pc);
  }

  red[t] = nloc; __syncthreads();
  for (int s = 128; s > 0; s >>= 1) { if (t < s) red[t] += red[t + s]; __syncthreads(); }
  double n = red[0]; __syncthreads();

  red[t] = bloc; __syncthreads();
  for (int s = 128; s > 0; s >>= 1) { if (t < s) red[t] += red[t + s]; __syncthreads(); }
  double B = red[0]; __syncthreads();

  red[t] = aloc; __syncthreads();
  for (int s = 128; s > 0; s >>= 1) { if (t < s) red[t] += red[t + s]; __syncthreads(); }
  double A = red[0]; __syncthreads();

  if (t == 0) {
    double ent = -(A / B - log(B));
    out[OFF_PERP] = (float)exp(ent);
    double M = sq[0] / (double)((size_t)N_ROWS * DIMS);
    out[OFF_LOSS] = (float)(1.5 * M);   // 0.5*commitment + codebook, both = M
  }

  float nf = (float)n;
  for (int c = t; c < NCODES; c += 256) {
    float ne = out[OFF_ECS + c];
    float cs = ((ne + EPSF) / (nf + (float)NCODES * EPSF)) * nf;
    csb[c] = cs < 0.01f ? 0.01f : cs;
  }
}

// ---------------- K4b: parallel finalize: ema_w + embedding ----------------
__global__ __launch_bounds__(256) void k4b_emb(const float* __restrict__ emaw_in,
                                               const float* __restrict__ dw,
                                               const float* __restrict__ csb,
                                               float* __restrict__ out) {
  int i = blockIdx.x * 256 + threadIdx.x;   // grid 256 -> 65536 threads
  int c = i >> 6;
  float nw = emaw_in[i] * DECAY + (1.0f - DECAY) * dw[i];
  out[OFF_EMAW + i] = nw;
  out[OFF_EMB + i] = nw / csb[c];
}

// ---------------- host ----------------
extern "C" void kernel_launch(void* const* d_in, const int* in_sizes, int n_in,
                              void* d_out, int out_size, void* d_ws, size_t ws_size,
                              hipStream_t stream) {
  const float* z    = (const float*)d_in[0];
  const float* emb  = (const float*)d_in[1];
  const float* ecs  = (const float*)d_in[2];
  const float* emaw = (const float*)d_in[3];
  float* out = (float*)d_out;

  char* ws = (char*)d_ws;
  double* sq     = (double*)(ws + 0);                    // 16 B
  int*    idxw   = (int*)   (ws + 16);                   // 512 KB
  uint*   clus   = (uint*)  (ws + 16 + 524288);          // 4 KB
  float*  dw     = (float*) (ws + 16 + 528384);          // 256 KB
  float*  ee     = (float*) (ws + 16 + 790528);          // 4 KB
  float*  csb    = (float*) (ws + 16 + 794624);          // 4 KB
  uint*   starts = (uint*)  (ws + 16 + 798720);          // 8 KB (1025 used)
  uint*   cursor = (uint*)  (ws + 16 + 806912);          // 4 KB
  uint*   rowids = (uint*)  (ws + 16 + 811008);          // 512 KB

  k0_init<<<4, 256, 0, stream>>>(emb, ee, clus, sq);
  k1_exact<<<N_ROWS / 64, 256, 0, stream>>>(z, emb, ee, idxw, out + OFF_IDX);
  k3a_gather<<<(N_ROWS * 16) / 256, 256, 0, stream>>>(z, emb, idxw, out + OFF_ZQ,
                                                      clus, sq);
  k3b_prefix<<<1, 256, 0, stream>>>(clus, starts, cursor);
  k3c_scatter<<<N_ROWS / 256, 256, 0, stream>>>(idxw, cursor, rowids);
  k3d_sum<<<NCODES, 256, 0, stream>>>(z, starts, rowids, dw);
  k4a_scalar<<<1, 256, 0, stream>>>(ecs, clus, sq, csb, out);
  k4b_emb<<<256, 256, 0, stream>>>(emaw, dw, csb, out);
}

// Round 7
// 334.804 us; speedup vs baseline: 1.5453x; 1.5453x over previous
//
#include <hip/hip_runtime.h>
#include <hip/hip_bf16.h>
#include <math.h>

#define N_ROWS   131072   // 8*16384
#define DIMS     64
#define NCODES   1024
#define DECAY    0.99f
#define EPSF     1e-5f
#define BAND     2e-3f    // approx-gap band; eps_approx ~2e-4, 5x margin

// d_out layout (float32 elements)
#define OFF_ZQ    0
#define OFF_IDX   8388608
#define OFF_LOSS  8519680
#define OFF_PERP  8519681
#define OFF_EMB   8519682
#define OFF_ECS   8585218
#define OFF_EMAW  8586242

typedef unsigned int uint;
typedef short bf16x8 __attribute__((ext_vector_type(8)));
typedef float f32x4  __attribute__((ext_vector_type(4)));

__device__ __forceinline__ double atomic_add_f64(double* p, double v) {
  return __hip_atomic_fetch_add(p, v, __ATOMIC_RELAXED, __HIP_MEMORY_SCOPE_AGENT);
}

__device__ __forceinline__ unsigned short bf16_rne(float f) {
  uint u = __float_as_uint(f);
  uint r = u + 0x7fffu + ((u >> 16) & 1u);
  return (unsigned short)(r >> 16);
}
__device__ __forceinline__ float bf16_f32(unsigned short h) {
  return __uint_as_float(((uint)h) << 16);
}

// numpy pairwise_sum base case (n=64): 8 strided accumulators, tree combine.
__device__ __forceinline__ float np_pairwise64_sq(const float* v) {
#pragma clang fp contract(off)
  float r[8];
#pragma unroll
  for (int j = 0; j < 8; ++j) r[j] = v[j] * v[j];
#pragma unroll
  for (int i = 8; i < 64; i += 8)
#pragma unroll
    for (int j = 0; j < 8; ++j) r[j] += v[i + j] * v[i + j];
  return ((r[0] + r[1]) + (r[2] + r[3])) + ((r[4] + r[5]) + (r[6] + r[7]));
}

// ---------------- K0: init ws + np-exact code norms ----------------
__global__ __launch_bounds__(256) void k0_init(const float* __restrict__ emb,
                                               float* __restrict__ ee,
                                               uint* __restrict__ cluster,
                                               double* __restrict__ sq,
                                               uint* __restrict__ cnt) {
  int gid = blockIdx.x * 256 + threadIdx.x;   // grid 4
  if (gid < NCODES) {
    cluster[gid] = 0u;
    float ev[DIMS];
    const float4* e4 = (const float4*)(emb + (size_t)gid * DIMS);
#pragma unroll
    for (int i = 0; i < 16; ++i) {
      float4 v = e4[i];
      ev[4*i] = v.x; ev[4*i+1] = v.y; ev[4*i+2] = v.z; ev[4*i+3] = v.w;
    }
    ee[gid] = np_pairwise64_sq(ev);
  }
  if (gid == 0) { *sq = 0.0; *cnt = 0u; }
}

// ---------------- K0b: pack codebook into bf16 hi/mid B-fragments ----------
// frag id = (T*2 + ktile)*2 + split; lane l: col = T*16 + (l&15),
// k = ktile*32 + (l>>4)*8 + i. Same (l,i)->k map as A packing (sigma-consistent).
__global__ __launch_bounds__(256) void k0b_pack(const float* __restrict__ emb,
                                                bf16x8* __restrict__ bsplit) {
  int T = blockIdx.x;                  // 64 code-tiles
  int l = threadIdx.x & 63;
  int slot = threadIdx.x >> 6;         // 0..3 = (ktile<<1)|split
  int ktile = slot >> 1, split = slot & 1;
  int code = T * 16 + (l & 15);
  int k0 = ktile * 32 + ((l >> 4) << 3);
  const float* ep = emb + (size_t)code * DIMS + k0;
  float4 fa = *(const float4*)ep;
  float4 fb = *(const float4*)(ep + 4);
  float fs[8] = {fa.x, fa.y, fa.z, fa.w, fb.x, fb.y, fb.z, fb.w};
  bf16x8 v;
#pragma unroll
  for (int i = 0; i < 8; ++i) {
    unsigned short h = bf16_rne(fs[i]);
    if (split == 0) v[i] = (short)h;
    else            v[i] = (short)bf16_rne(fs[i] - bf16_f32(h));
  }
  bsplit[(size_t)((T * 2 + ktile) * 2 + split) * 64 + l] = v;
}

// ---------------- K1: MFMA approx argmin + gap flag ------------------------
// Block = 4 waves; wave w owns 16 rows (rowbase + l&15 for A). 3 split passes
// (hi*ehi + hi*emid + mid*ehi) x 2 k-tiles = 6 mfma per 16-code tile, one
// f32x4 acc. s = ee - 2*dot (zz dropped: row-constant). Per (lane,reg) running
// best/second/idx over 64 tiles, then 16-lane xor-reduce. Gap < BAND -> row
// queued for exact recheck (also covers exact approx-ties, gap 0).
__global__ __launch_bounds__(256) void k1_mfma(const float* __restrict__ z,
                                               const bf16x8* __restrict__ bsplit,
                                               const float* __restrict__ ee,
                                               int* __restrict__ idx_out,
                                               float* __restrict__ idx_f_out,
                                               uint* __restrict__ cnt,
                                               uint* __restrict__ list) {
  int l = threadIdx.x & 63;
  int w = threadIdx.x >> 6;
  int rowbase = blockIdx.x * 64 + w * 16;
  int arow = rowbase + (l & 15);
  int kq = (l >> 4) << 3;              // 0,8,16,24

  // A fragments: z row split into bf16 hi/mid, same (l,i)->k map as B
  bf16x8 ahi[2], ami[2];
#pragma unroll
  for (int t = 0; t < 2; ++t) {
    const float* zp = z + (size_t)arow * DIMS + t * 32 + kq;
    float4 fa = *(const float4*)zp;
    float4 fb = *(const float4*)(zp + 4);
    float fs[8] = {fa.x, fa.y, fa.z, fa.w, fb.x, fb.y, fb.z, fb.w};
#pragma unroll
    for (int i = 0; i < 8; ++i) {
      unsigned short h = bf16_rne(fs[i]);
      ahi[t][i] = (short)h;
      ami[t][i] = (short)bf16_rne(fs[i] - bf16_f32(h));
    }
  }

  float best[4]  = {3.4e38f, 3.4e38f, 3.4e38f, 3.4e38f};
  float second[4] = {3.4e38f, 3.4e38f, 3.4e38f, 3.4e38f};
  int   bidx[4] = {0, 0, 0, 0};
  int   col = l & 15;

#pragma unroll 2
  for (int T = 0; T < 64; ++T) {
    const bf16x8* bp = bsplit + (size_t)(T * 4) * 64 + l;
    bf16x8 bhi0 = bp[0];          // (T,kt0,hi)
    bf16x8 bmi0 = bp[64];         // (T,kt0,mid)
    bf16x8 bhi1 = bp[128];        // (T,kt1,hi)
    bf16x8 bmi1 = bp[192];        // (T,kt1,mid)
    f32x4 acc = {0.f, 0.f, 0.f, 0.f};
    acc = __builtin_amdgcn_mfma_f32_16x16x32_bf16(ahi[0], bhi0, acc, 0, 0, 0);
    acc = __builtin_amdgcn_mfma_f32_16x16x32_bf16(ahi[1], bhi1, acc, 0, 0, 0);
    acc = __builtin_amdgcn_mfma_f32_16x16x32_bf16(ahi[0], bmi0, acc, 0, 0, 0);
    acc = __builtin_amdgcn_mfma_f32_16x16x32_bf16(ahi[1], bmi1, acc, 0, 0, 0);
    acc = __builtin_amdgcn_mfma_f32_16x16x32_bf16(ami[0], bhi0, acc, 0, 0, 0);
    acc = __builtin_amdgcn_mfma_f32_16x16x32_bf16(ami[1], bhi1, acc, 0, 0, 0);

    int code = T * 16 + col;
    float eeT = ee[code];
#pragma unroll
    for (int j = 0; j < 4; ++j) {
      float s = fmaf(-2.0f, acc[j], eeT);
      bool lt = s < best[j];
      second[j] = lt ? best[j] : fminf(second[j], s);
      best[j]   = lt ? s : best[j];
      bidx[j]   = lt ? code : bidx[j];
    }
  }

  // reduce (best, second, idx) across the 16 lanes sharing l>>4
#pragma unroll
  for (int m = 1; m < 16; m <<= 1) {
#pragma unroll
    for (int j = 0; j < 4; ++j) {
      float ob = __shfl_xor(best[j], m, 64);
      float os = __shfl_xor(second[j], m, 64);
      int   oi = __shfl_xor(bidx[j], m, 64);
      if (ob < best[j]) {
        second[j] = fminf(os, best[j]);
        best[j] = ob; bidx[j] = oi;
      } else if (ob == best[j]) {
        bidx[j] = min(bidx[j], oi);
        second[j] = fminf(second[j], fminf(os, ob));  // dup min -> gap 0
      } else {
        second[j] = fminf(second[j], ob);
      }
    }
  }

  if (col == 0) {
#pragma unroll
    for (int j = 0; j < 4; ++j) {
      int r = rowbase + ((l >> 4) << 2) + j;
      idx_out[r] = bidx[j];
      idx_f_out[r] = (float)bidx[j];
      if (second[j] - best[j] < BAND) {
        uint p = atomicAdd(cnt, 1u);
        list[p] = (uint)r;
      }
    }
  }
}

// ---------------- K2: exact recheck of near-tie rows (numpy-f32 bit-exact) --
// Replicates the round-2-proven math: zz = np pairwise, dot = sequential
// single-acc FMA, d = fmaf(-2, dot, zz+ee[c]); ascending strict < + lowest-
// index block reduce == numpy first-index argmin over all 1024 codes.
__global__ __launch_bounds__(256) void k2_recheck(const float* __restrict__ z,
                                                  const float* __restrict__ emb,
                                                  const float* __restrict__ ee,
                                                  const uint* __restrict__ cnt,
                                                  const uint* __restrict__ list,
                                                  int* __restrict__ idx_out,
                                                  float* __restrict__ idx_f_out) {
#pragma clang fp contract(off)
  __shared__ float zrow[DIMS];
  __shared__ float rv[256];
  __shared__ int   ri[256];
  int t = threadIdx.x;
  uint n = *cnt;
  for (uint i = blockIdx.x; i < n; i += gridDim.x) {
    uint row = list[i];
    __syncthreads();
    if (t < 16)
      ((float4*)zrow)[t] = ((const float4*)(z + (size_t)row * DIMS))[t];
    __syncthreads();
    float zz = np_pairwise64_sq(zrow);
    float best = 3.4e38f; int bi = 0;
#pragma unroll
    for (int k4 = 0; k4 < 4; ++k4) {
      int c = t * 4 + k4;                      // ascending codes per thread
      const float* e = emb + (size_t)c * DIMS;
      float a = 0.f;
      for (int k = 0; k < DIMS; ++k) a = fmaf(zrow[k], e[k], a);
      float d = fmaf(-2.0f, a, zz + ee[c]);
      if (d < best) { best = d; bi = c; }
    }
    rv[t] = best; ri[t] = bi;
    __syncthreads();
    for (int s = 128; s > 0; s >>= 1) {
      if (t < s) {
        float ov = rv[t + s]; int oi = ri[t + s];
        if (ov < rv[t] || (ov == rv[t] && oi < ri[t])) { rv[t] = ov; ri[t] = oi; }
      }
      __syncthreads();
    }
    if (t == 0) { idx_out[row] = ri[0]; idx_f_out[row] = (float)ri[0]; }
  }
}

// ---------------- K3a: zq write, loss accum, cluster counts ----------------
__global__ __launch_bounds__(256) void k3a_gather(const float* __restrict__ z,
                                                  const float* __restrict__ emb,
                                                  const int* __restrict__ idx,
                                                  float* __restrict__ out_zq,
                                                  uint* __restrict__ cluster,
                                                  double* __restrict__ sq) {
  int gid = blockIdx.x * 256 + threadIdx.x;   // over N_ROWS*16 float4s
  int row = gid >> 4, d4 = gid & 15;
  int code = idx[row];

  float4 zv = ((const float4*)z)[gid];
  float4 ev = ((const float4*)emb)[code * 16 + d4];

  float dx = ev.x - zv.x, dy = ev.y - zv.y, dz = ev.z - zv.z, dw_ = ev.w - zv.w;
  float4 o;
  o.x = zv.x + dx; o.y = zv.y + dy; o.z = zv.z + dz; o.w = zv.w + dw_;
  ((float4*)out_zq)[gid] = o;

  float ss = dx * dx + dy * dy + dz * dz + dw_ * dw_;

  if (d4 == 0) atomicAdd(&cluster[code], 1u);

  double bs = (double)ss;
#pragma unroll
  for (int o2 = 32; o2 > 0; o2 >>= 1) bs += __shfl_down(bs, o2, 64);
  __shared__ double wsum[4];
  int lane = threadIdx.x & 63, wid = threadIdx.x >> 6;
  if (lane == 0) wsum[wid] = bs;
  __syncthreads();
  if (threadIdx.x == 0) {
    double tt = (wsum[0] + wsum[1]) + (wsum[2] + wsum[3]);
    atomic_add_f64(sq, tt);
  }
}

// ---------------- K3b: exclusive prefix over counts (1 block) --------------
__global__ __launch_bounds__(256) void k3b_prefix(const uint* __restrict__ cluster,
                                                  uint* __restrict__ starts,
                                                  uint* __restrict__ cursor) {
  __shared__ uint a[256], b[256];
  int t = threadIdx.x;
  uint c0 = cluster[t*4+0], c1 = cluster[t*4+1], c2 = cluster[t*4+2], c3 = cluster[t*4+3];
  uint s = c0 + c1 + c2 + c3;
  a[t] = s;
  __syncthreads();
  uint* src = a; uint* dst = b;
  for (int off = 1; off < 256; off <<= 1) {
    dst[t] = src[t] + ((t >= off) ? src[t - off] : 0u);
    __syncthreads();
    uint* tmp = src; src = dst; dst = tmp;
  }
  uint base = (t > 0) ? src[t-1] : 0u;
  uint p0 = base, p1 = p0 + c0, p2 = p1 + c1, p3 = p2 + c2;
  starts[t*4+0] = p0; starts[t*4+1] = p1; starts[t*4+2] = p2; starts[t*4+3] = p3;
  cursor[t*4+0] = p0; cursor[t*4+1] = p1; cursor[t*4+2] = p2; cursor[t*4+3] = p3;
  if (t == 255) starts[NCODES] = src[255];
}

// ---------------- K3c: scatter row ids into code buckets -------------------
__global__ __launch_bounds__(256) void k3c_scatter(const int* __restrict__ idx,
                                                   uint* __restrict__ cursor,
                                                   uint* __restrict__ rowids) {
  int row = blockIdx.x * 256 + threadIdx.x;
  int code = idx[row];
  uint pos = atomicAdd(&cursor[code], 1u);
  rowids[pos] = (uint)row;
}

// ---------------- K3d: per-code segmented sum (block per code) -------------
__global__ __launch_bounds__(256) void k3d_sum(const float* __restrict__ z,
                                               const uint* __restrict__ starts,
                                               const uint* __restrict__ rowids,
                                               float* __restrict__ dw) {
  __shared__ float acc[4][64];
  int code = blockIdx.x;
  int lane = threadIdx.x & 63, w = threadIdx.x >> 6;
  uint s0 = starts[code], s1 = starts[code + 1];
  float s = 0.f;
  for (uint i = s0 + (uint)w; i < s1; i += 4) {
    uint r = rowids[i];
    s += z[(size_t)r * DIMS + lane];
  }
  acc[w][lane] = s;
  __syncthreads();
  if (threadIdx.x < 64) {
    float v = (acc[0][threadIdx.x] + acc[1][threadIdx.x])
            + (acc[2][threadIdx.x] + acc[3][threadIdx.x]);
    dw[code * DIMS + threadIdx.x] = v;
  }
}

// ---------------- K4a: serial finalize (1 block) ---------------------------
__global__ __launch_bounds__(256) void k4a_scalar(const float* __restrict__ ecs_in,
                                                  const uint* __restrict__ cluster,
                                                  const double* __restrict__ sq,
                                                  float* __restrict__ csb,
                                                  float* __restrict__ out) {
  __shared__ double red[256];
  int t = threadIdx.x;

  double nloc = 0.0, aloc = 0.0, bloc = 0.0;
  for (int c = t; c < NCODES; c += 256) {
    float cntf = (float)cluster[c];
    float ne = ecs_in[c] * DECAY + (1.0f - DECAY) * cntf;
    out[OFF_ECS + c] = ne;
    nloc += (double)ne;
    double p = (double)cntf / (double)N_ROWS;
    double pc = p < 1e-10 ? 1e-10 : p;
    bloc += pc;
    aloc += pc * log(pc);
  }

  red[t] = nloc; __syncthreads();
  for (int s = 128; s > 0; s >>= 1) { if (t < s) red[t] += red[t + s]; __syncthreads(); }
  double n = red[0]; __syncthreads();

  red[t] = bloc; __syncthreads();
  for (int s = 128; s > 0; s >>= 1) { if (t < s) red[t] += red[t + s]; __syncthreads(); }
  double B = red[0]; __syncthreads();

  red[t] = aloc; __syncthreads();
  for (int s = 128; s > 0; s >>= 1) { if (t < s) red[t] += red[t + s]; __syncthreads(); }
  double A = red[0]; __syncthreads();

  if (t == 0) {
    double ent = -(A / B - log(B));
    out[OFF_PERP] = (float)exp(ent);
    double M = sq[0] / (double)((size_t)N_ROWS * DIMS);
    out[OFF_LOSS] = (float)(1.5 * M);
  }

  float nf = (float)n;
  for (int c = t; c < NCODES; c += 256) {
    float ne = out[OFF_ECS + c];
    float cs = ((ne + EPSF) / (nf + (float)NCODES * EPSF)) * nf;
    csb[c] = cs < 0.01f ? 0.01f : cs;
  }
}

// ---------------- K4b: parallel finalize: ema_w + embedding ----------------
__global__ __launch_bounds__(256) void k4b_emb(const float* __restrict__ emaw_in,
                                               const float* __restrict__ dw,
                                               const float* __restrict__ csb,
                                               float* __restrict__ out) {
  int i = blockIdx.x * 256 + threadIdx.x;
  int c = i >> 6;
  float nw = emaw_in[i] * DECAY + (1.0f - DECAY) * dw[i];
  out[OFF_EMAW + i] = nw;
  out[OFF_EMB + i] = nw / csb[c];
}

// ---------------- host ----------------
extern "C" void kernel_launch(void* const* d_in, const int* in_sizes, int n_in,
                              void* d_out, int out_size, void* d_ws, size_t ws_size,
                              hipStream_t stream) {
  const float* z    = (const float*)d_in[0];
  const float* emb  = (const float*)d_in[1];
  const float* ecs  = (const float*)d_in[2];
  const float* emaw = (const float*)d_in[3];
  float* out = (float*)d_out;

  char* ws = (char*)d_ws;
  double* sq     = (double*) (ws + 0);          // 16 B
  uint*   cnt    = (uint*)   (ws + 16);         // 16 B
  int*    idxw   = (int*)    (ws + 32);         // 512 KB
  uint*   clus   = (uint*)   (ws + 524320);     // 4 KB
  float*  dw     = (float*)  (ws + 528416);     // 256 KB
  float*  ee     = (float*)  (ws + 790560);     // 4 KB
  float*  csb    = (float*)  (ws + 794656);     // 4 KB
  uint*   starts = (uint*)   (ws + 798752);     // 8 KB
  uint*   cursor = (uint*)   (ws + 806944);     // 4 KB
  uint*   rowids = (uint*)   (ws + 811040);     // 512 KB
  bf16x8* bsplit = (bf16x8*) (ws + 1335328);    // 256 KB
  uint*   rlist  = (uint*)   (ws + 1597472);    // 512 KB

  k0_init<<<4, 256, 0, stream>>>(emb, ee, clus, sq, cnt);
  k0b_pack<<<64, 256, 0, stream>>>(emb, bsplit);
  k1_mfma<<<N_ROWS / 64, 256, 0, stream>>>(z, bsplit, ee, idxw, out + OFF_IDX,
                                           cnt, rlist);
  k2_recheck<<<1024, 256, 0, stream>>>(z, emb, ee, cnt, rlist, idxw, out + OFF_IDX);
  k3a_gather<<<(N_ROWS * 16) / 256, 256, 0, stream>>>(z, emb, idxw, out + OFF_ZQ,
                                                      clus, sq);
  k3b_prefix<<<1, 256, 0, stream>>>(clus, starts, cursor);
  k3c_scatter<<<N_ROWS / 256, 256, 0, stream>>>(idxw, cursor, rowids);
  k3d_sum<<<NCODES, 256, 0, stream>>>(z, starts, rowids, dw);
  k4a_scalar<<<1, 256, 0, stream>>>(ecs, clus, sq, csb, out);
  k4b_emb<<<256, 256, 0, stream>>>(emaw, dw, csb, out);
}

// Round 8
// 263.934 us; speedup vs baseline: 1.9603x; 1.2685x over previous
//
#include <hip/hip_runtime.h>
#include <hip/hip_bf16.h>
#include <math.h>

#define N_ROWS   131072   // 8*16384
#define DIMS     64
#define NCODES   1024
#define DECAY    0.99f
#define EPSF     1e-5f
#define BAND     2e-3f    // approx-gap band; eps_approx ~2e-4, 5x margin

// d_out layout (float32 elements)
#define OFF_ZQ    0
#define OFF_IDX   8388608
#define OFF_LOSS  8519680
#define OFF_PERP  8519681
#define OFF_EMB   8519682
#define OFF_ECS   8585218
#define OFF_EMAW  8586242

typedef unsigned int uint;
typedef short bf16x8 __attribute__((ext_vector_type(8)));
typedef float f32x4  __attribute__((ext_vector_type(4)));

__device__ __forceinline__ unsigned short bf16_rne(float f) {
  uint u = __float_as_uint(f);
  uint r = u + 0x7fffu + ((u >> 16) & 1u);
  return (unsigned short)(r >> 16);
}
__device__ __forceinline__ float bf16_f32(unsigned short h) {
  return __uint_as_float(((uint)h) << 16);
}

// numpy pairwise_sum base case (n=64): 8 strided accumulators, tree combine.
__device__ __forceinline__ float np_pairwise64_sq(const float* v) {
#pragma clang fp contract(off)
  float r[8];
#pragma unroll
  for (int j = 0; j < 8; ++j) r[j] = v[j] * v[j];
#pragma unroll
  for (int i = 8; i < 64; i += 8)
#pragma unroll
    for (int j = 0; j < 8; ++j) r[j] += v[i + j] * v[i + j];
  return ((r[0] + r[1]) + (r[2] + r[3])) + ((r[4] + r[5]) + (r[6] + r[7]));
}

// ---------------- K0: init ws + np-exact code norms ----------------
__global__ __launch_bounds__(256) void k0_init(const float* __restrict__ emb,
                                               float* __restrict__ ee,
                                               uint* __restrict__ cluster,
                                               uint* __restrict__ cnt) {
  int gid = blockIdx.x * 256 + threadIdx.x;   // grid 4
  if (gid < NCODES) {
    cluster[gid] = 0u;
    float ev[DIMS];
    const float4* e4 = (const float4*)(emb + (size_t)gid * DIMS);
#pragma unroll
    for (int i = 0; i < 16; ++i) {
      float4 v = e4[i];
      ev[4*i] = v.x; ev[4*i+1] = v.y; ev[4*i+2] = v.z; ev[4*i+3] = v.w;
    }
    ee[gid] = np_pairwise64_sq(ev);
  }
  if (gid == 0) { *cnt = 0u; }
}

// ---------------- K0b: pack codebook into bf16 hi/mid B-fragments ----------
// frag id = (T*2 + ktile)*2 + split; lane l: col = T*16 + (l&15),
// k = ktile*32 + (l>>4)*8 + i. Same (l,i)->k map as A packing (sigma-consistent).
__global__ __launch_bounds__(256) void k0b_pack(const float* __restrict__ emb,
                                                bf16x8* __restrict__ bsplit) {
  int T = blockIdx.x;                  // 64 code-tiles
  int l = threadIdx.x & 63;
  int slot = threadIdx.x >> 6;         // 0..3 = (ktile<<1)|split
  int ktile = slot >> 1, split = slot & 1;
  int code = T * 16 + (l & 15);
  int k0 = ktile * 32 + ((l >> 4) << 3);
  const float* ep = emb + (size_t)code * DIMS + k0;
  float4 fa = *(const float4*)ep;
  float4 fb = *(const float4*)(ep + 4);
  float fs[8] = {fa.x, fa.y, fa.z, fa.w, fb.x, fb.y, fb.z, fb.w};
  bf16x8 v;
#pragma unroll
  for (int i = 0; i < 8; ++i) {
    unsigned short h = bf16_rne(fs[i]);
    if (split == 0) v[i] = (short)h;
    else            v[i] = (short)bf16_rne(fs[i] - bf16_f32(h));
  }
  bsplit[(size_t)((T * 2 + ktile) * 2 + split) * 64 + l] = v;
}

// ---------------- K1: MFMA approx argmin + gap flag ------------------------
// Block = 4 waves; wave w owns 16 rows (rowbase + l&15 for A). 3 split passes
// (hi*ehi + hi*emid + mid*ehi) x 2 k-tiles = 6 mfma per 16-code tile, one
// f32x4 acc. s = ee - 2*dot (zz dropped: row-constant). Per (lane,reg) running
// best/second/idx over 64 tiles, then 16-lane xor-reduce. Gap < BAND -> row
// queued for exact recheck (also covers exact approx-ties, gap 0).
__global__ __launch_bounds__(256) void k1_mfma(const float* __restrict__ z,
                                               const bf16x8* __restrict__ bsplit,
                                               const float* __restrict__ ee,
                                               int* __restrict__ idx_out,
                                               float* __restrict__ idx_f_out,
                                               uint* __restrict__ cnt,
                                               uint* __restrict__ list) {
  int l = threadIdx.x & 63;
  int w = threadIdx.x >> 6;
  int rowbase = blockIdx.x * 64 + w * 16;
  int arow = rowbase + (l & 15);
  int kq = (l >> 4) << 3;              // 0,8,16,24

  // A fragments: z row split into bf16 hi/mid, same (l,i)->k map as B
  bf16x8 ahi[2], ami[2];
#pragma unroll
  for (int t = 0; t < 2; ++t) {
    const float* zp = z + (size_t)arow * DIMS + t * 32 + kq;
    float4 fa = *(const float4*)zp;
    float4 fb = *(const float4*)(zp + 4);
    float fs[8] = {fa.x, fa.y, fa.z, fa.w, fb.x, fb.y, fb.z, fb.w};
#pragma unroll
    for (int i = 0; i < 8; ++i) {
      unsigned short h = bf16_rne(fs[i]);
      ahi[t][i] = (short)h;
      ami[t][i] = (short)bf16_rne(fs[i] - bf16_f32(h));
    }
  }

  float best[4]  = {3.4e38f, 3.4e38f, 3.4e38f, 3.4e38f};
  float second[4] = {3.4e38f, 3.4e38f, 3.4e38f, 3.4e38f};
  int   bidx[4] = {0, 0, 0, 0};
  int   col = l & 15;

#pragma unroll 2
  for (int T = 0; T < 64; ++T) {
    const bf16x8* bp = bsplit + (size_t)(T * 4) * 64 + l;
    bf16x8 bhi0 = bp[0];          // (T,kt0,hi)
    bf16x8 bmi0 = bp[64];         // (T,kt0,mid)
    bf16x8 bhi1 = bp[128];        // (T,kt1,hi)
    bf16x8 bmi1 = bp[192];        // (T,kt1,mid)
    f32x4 acc = {0.f, 0.f, 0.f, 0.f};
    acc = __builtin_amdgcn_mfma_f32_16x16x32_bf16(ahi[0], bhi0, acc, 0, 0, 0);
    acc = __builtin_amdgcn_mfma_f32_16x16x32_bf16(ahi[1], bhi1, acc, 0, 0, 0);
    acc = __builtin_amdgcn_mfma_f32_16x16x32_bf16(ahi[0], bmi0, acc, 0, 0, 0);
    acc = __builtin_amdgcn_mfma_f32_16x16x32_bf16(ahi[1], bmi1, acc, 0, 0, 0);
    acc = __builtin_amdgcn_mfma_f32_16x16x32_bf16(ami[0], bhi0, acc, 0, 0, 0);
    acc = __builtin_amdgcn_mfma_f32_16x16x32_bf16(ami[1], bhi1, acc, 0, 0, 0);

    int code = T * 16 + col;
    float eeT = ee[code];
#pragma unroll
    for (int j = 0; j < 4; ++j) {
      float s = fmaf(-2.0f, acc[j], eeT);
      bool lt = s < best[j];
      second[j] = lt ? best[j] : fminf(second[j], s);
      best[j]   = lt ? s : best[j];
      bidx[j]   = lt ? code : bidx[j];
    }
  }

  // reduce (best, second, idx) across the 16 lanes sharing l>>4
#pragma unroll
  for (int m = 1; m < 16; m <<= 1) {
#pragma unroll
    for (int j = 0; j < 4; ++j) {
      float ob = __shfl_xor(best[j], m, 64);
      float os = __shfl_xor(second[j], m, 64);
      int   oi = __shfl_xor(bidx[j], m, 64);
      if (ob < best[j]) {
        second[j] = fminf(os, best[j]);
        best[j] = ob; bidx[j] = oi;
      } else if (ob == best[j]) {
        bidx[j] = min(bidx[j], oi);
        second[j] = fminf(second[j], fminf(os, ob));  // dup min -> gap 0
      } else {
        second[j] = fminf(second[j], ob);
      }
    }
  }

  if (col == 0) {
#pragma unroll
    for (int j = 0; j < 4; ++j) {
      int r = rowbase + ((l >> 4) << 2) + j;
      idx_out[r] = bidx[j];
      idx_f_out[r] = (float)bidx[j];
      if (second[j] - best[j] < BAND) {
        uint p = atomicAdd(cnt, 1u);
        list[p] = (uint)r;
      }
    }
  }
}

// ---------------- K2: exact recheck of near-tie rows (numpy-f32 bit-exact) --
__global__ __launch_bounds__(256) void k2_recheck(const float* __restrict__ z,
                                                  const float* __restrict__ emb,
                                                  const float* __restrict__ ee,
                                                  const uint* __restrict__ cnt,
                                                  const uint* __restrict__ list,
                                                  int* __restrict__ idx_out,
                                                  float* __restrict__ idx_f_out) {
#pragma clang fp contract(off)
  __shared__ float zrow[DIMS];
  __shared__ float rv[256];
  __shared__ int   ri[256];
  int t = threadIdx.x;
  uint n = *cnt;
  for (uint i = blockIdx.x; i < n; i += gridDim.x) {
    uint row = list[i];
    __syncthreads();
    if (t < 16)
      ((float4*)zrow)[t] = ((const float4*)(z + (size_t)row * DIMS))[t];
    __syncthreads();
    float zz = np_pairwise64_sq(zrow);
    float best = 3.4e38f; int bi = 0;
#pragma unroll
    for (int k4 = 0; k4 < 4; ++k4) {
      int c = t * 4 + k4;                      // ascending codes per thread
      const float* e = emb + (size_t)c * DIMS;
      float a = 0.f;
      for (int k = 0; k < DIMS; ++k) a = fmaf(zrow[k], e[k], a);
      float d = fmaf(-2.0f, a, zz + ee[c]);
      if (d < best) { best = d; bi = c; }
    }
    rv[t] = best; ri[t] = bi;
    __syncthreads();
    for (int s = 128; s > 0; s >>= 1) {
      if (t < s) {
        float ov = rv[t + s]; int oi = ri[t + s];
        if (ov < rv[t] || (ov == rv[t] && oi < ri[t])) { rv[t] = ov; ri[t] = oi; }
      }
      __syncthreads();
    }
    if (t == 0) { idx_out[row] = ri[0]; idx_f_out[row] = (float)ri[0]; }
  }
}

// ---------------- KC: cluster counts (u32 atomics over 1024 addrs) ---------
__global__ __launch_bounds__(256) void kc_count(const int* __restrict__ idx,
                                                uint* __restrict__ cluster) {
  int row = blockIdx.x * 256 + threadIdx.x;
  atomicAdd(&cluster[idx[row]], 1u);
}

// ---------------- K3b: exclusive prefix over counts (1 block) --------------
__global__ __launch_bounds__(256) void k3b_prefix(const uint* __restrict__ cluster,
                                                  uint* __restrict__ starts,
                                                  uint* __restrict__ cursor) {
  __shared__ uint a[256], b[256];
  int t = threadIdx.x;
  uint c0 = cluster[t*4+0], c1 = cluster[t*4+1], c2 = cluster[t*4+2], c3 = cluster[t*4+3];
  uint s = c0 + c1 + c2 + c3;
  a[t] = s;
  __syncthreads();
  uint* src = a; uint* dst = b;
  for (int off = 1; off < 256; off <<= 1) {
    dst[t] = src[t] + ((t >= off) ? src[t - off] : 0u);
    __syncthreads();
    uint* tmp = src; src = dst; dst = tmp;
  }
  uint base = (t > 0) ? src[t-1] : 0u;
  uint p0 = base, p1 = p0 + c0, p2 = p1 + c1, p3 = p2 + c2;
  starts[t*4+0] = p0; starts[t*4+1] = p1; starts[t*4+2] = p2; starts[t*4+3] = p3;
  cursor[t*4+0] = p0; cursor[t*4+1] = p1; cursor[t*4+2] = p2; cursor[t*4+3] = p3;
  if (t == 255) starts[NCODES] = src[255];
}

// ---------------- K3c: scatter row ids into code buckets -------------------
__global__ __launch_bounds__(256) void k3c_scatter(const int* __restrict__ idx,
                                                   uint* __restrict__ cursor,
                                                   uint* __restrict__ rowids) {
  int row = blockIdx.x * 256 + threadIdx.x;
  int code = idx[row];
  uint pos = atomicAdd(&cursor[code], 1u);
  rowids[pos] = (uint)row;
}

// ---------------- K3d: fused per-code pass: zq + loss + dw -----------------
// Block = code. emb row read ONCE into registers (no per-row dependent
// gather); z rows streamed 256B-coalesced per wave; zq written with the
// identical o = zv + (ev - zv) op sequence; d^2 accumulated per-thread in
// f64; per-block partial -> sqpart[code] (plain store, NO f64 atomics --
// round-7 k3a lost ~90us to 8192 same-address f64 atomics).
__global__ __launch_bounds__(256) void k3d_fused(const float* __restrict__ z,
                                                 const float* __restrict__ emb,
                                                 const uint* __restrict__ starts,
                                                 const uint* __restrict__ rowids,
                                                 float* __restrict__ out_zq,
                                                 float* __restrict__ dw,
                                                 double* __restrict__ sqpart) {
  __shared__ float  accf[4][64];
  __shared__ double accd[4][64];
  int code = blockIdx.x;
  int lane = threadIdx.x & 63, w = threadIdx.x >> 6;
  uint s0 = starts[code], s1 = starts[code + 1];
  float ev = emb[code * DIMS + lane];
  float fs = 0.f;
  double ds = 0.0;
  for (uint i = s0 + (uint)w; i < s1; i += 4) {
    uint r = rowids[i];                       // wave-uniform -> s_load
    float zv = z[(size_t)r * DIMS + lane];    // 256B coalesced per wave
    float d = ev - zv;
    float o = zv + d;                         // z_q_st, op-for-op as before
    out_zq[(size_t)r * DIMS + lane] = o;
    fs += zv;
    ds += (double)(d * d);
  }
  accf[w][lane] = fs; accd[w][lane] = ds;
  __syncthreads();
  if (threadIdx.x < 64) {
    float v = (accf[0][threadIdx.x] + accf[1][threadIdx.x])
            + (accf[2][threadIdx.x] + accf[3][threadIdx.x]);
    dw[code * DIMS + threadIdx.x] = v;
    double sd = (accd[0][threadIdx.x] + accd[1][threadIdx.x])
              + (accd[2][threadIdx.x] + accd[3][threadIdx.x]);
#pragma unroll
    for (int o2 = 32; o2 > 0; o2 >>= 1) sd += __shfl_down(sd, o2, 64);
    if (threadIdx.x == 0) sqpart[code] = sd;
  }
}

// ---------------- K4a: serial finalize (1 block) ---------------------------
__global__ __launch_bounds__(256) void k4a_scalar(const float* __restrict__ ecs_in,
                                                  const uint* __restrict__ cluster,
                                                  const double* __restrict__ sqpart,
                                                  float* __restrict__ csb,
                                                  float* __restrict__ out) {
  __shared__ double red[256];
  int t = threadIdx.x;

  double nloc = 0.0, aloc = 0.0, bloc = 0.0, sloc = 0.0;
  for (int c = t; c < NCODES; c += 256) {
    float cntf = (float)cluster[c];
    float ne = ecs_in[c] * DECAY + (1.0f - DECAY) * cntf;
    out[OFF_ECS + c] = ne;
    nloc += (double)ne;
    double p = (double)cntf / (double)N_ROWS;
    double pc = p < 1e-10 ? 1e-10 : p;
    bloc += pc;
    aloc += pc * log(pc);
    sloc += sqpart[c];
  }

  red[t] = nloc; __syncthreads();
  for (int s = 128; s > 0; s >>= 1) { if (t < s) red[t] += red[t + s]; __syncthreads(); }
  double n = red[0]; __syncthreads();

  red[t] = bloc; __syncthreads();
  for (int s = 128; s > 0; s >>= 1) { if (t < s) red[t] += red[t + s]; __syncthreads(); }
  double B = red[0]; __syncthreads();

  red[t] = aloc; __syncthreads();
  for (int s = 128; s > 0; s >>= 1) { if (t < s) red[t] += red[t + s]; __syncthreads(); }
  double A = red[0]; __syncthreads();

  red[t] = sloc; __syncthreads();
  for (int s = 128; s > 0; s >>= 1) { if (t < s) red[t] += red[t + s]; __syncthreads(); }
  double S = red[0]; __syncthreads();

  if (t == 0) {
    double ent = -(A / B - log(B));
    out[OFF_PERP] = (float)exp(ent);
    double M = S / (double)((size_t)N_ROWS * DIMS);
    out[OFF_LOSS] = (float)(1.5 * M);   // 0.5*commitment + codebook, both = M
  }

  float nf = (float)n;
  for (int c = t; c < NCODES; c += 256) {
    float ne = out[OFF_ECS + c];
    float cs = ((ne + EPSF) / (nf + (float)NCODES * EPSF)) * nf;
    csb[c] = cs < 0.01f ? 0.01f : cs;
  }
}

// ---------------- K4b: parallel finalize: ema_w + embedding ----------------
__global__ __launch_bounds__(256) void k4b_emb(const float* __restrict__ emaw_in,
                                               const float* __restrict__ dw,
                                               const float* __restrict__ csb,
                                               float* __restrict__ out) {
  int i = blockIdx.x * 256 + threadIdx.x;
  int c = i >> 6;
  float nw = emaw_in[i] * DECAY + (1.0f - DECAY) * dw[i];
  out[OFF_EMAW + i] = nw;
  out[OFF_EMB + i] = nw / csb[c];
}

// ---------------- host ----------------
extern "C" void kernel_launch(void* const* d_in, const int* in_sizes, int n_in,
                              void* d_out, int out_size, void* d_ws, size_t ws_size,
                              hipStream_t stream) {
  const float* z    = (const float*)d_in[0];
  const float* emb  = (const float*)d_in[1];
  const float* ecs  = (const float*)d_in[2];
  const float* emaw = (const float*)d_in[3];
  float* out = (float*)d_out;

  char* ws = (char*)d_ws;
  uint*   cnt    = (uint*)   (ws + 0);          // 16 B
  int*    idxw   = (int*)    (ws + 16);         // 512 KB
  uint*   clus   = (uint*)   (ws + 524304);     // 4 KB
  float*  dw     = (float*)  (ws + 528416);     // 256 KB
  float*  ee     = (float*)  (ws + 790560);     // 4 KB
  float*  csb    = (float*)  (ws + 794656);     // 4 KB
  uint*   starts = (uint*)   (ws + 798752);     // 8 KB
  uint*   cursor = (uint*)   (ws + 806944);     // 4 KB
  uint*   rowids = (uint*)   (ws + 811040);     // 512 KB
  bf16x8* bsplit = (bf16x8*) (ws + 1335328);    // 256 KB
  uint*   rlist  = (uint*)   (ws + 1597472);    // 512 KB
  // sqpart overlaps rlist: rlist is dead after k2_recheck, sqpart written in
  // k3d (stream-ordered after k2). 1024 doubles = 8 KB.
  double* sqpart = (double*) (ws + 1597472);

  k0_init<<<4, 256, 0, stream>>>(emb, ee, clus, cnt);
  k0b_pack<<<64, 256, 0, stream>>>(emb, bsplit);
  k1_mfma<<<N_ROWS / 64, 256, 0, stream>>>(z, bsplit, ee, idxw, out + OFF_IDX,
                                           cnt, rlist);
  k2_recheck<<<1024, 256, 0, stream>>>(z, emb, ee, cnt, rlist, idxw, out + OFF_IDX);
  kc_count<<<N_ROWS / 256, 256, 0, stream>>>(idxw, clus);
  k3b_prefix<<<1, 256, 0, stream>>>(clus, starts, cursor);
  k3c_scatter<<<N_ROWS / 256, 256, 0, stream>>>(idxw, cursor, rowids);
  k3d_fused<<<NCODES, 256, 0, stream>>>(z, emb, starts, rowids, out + OFF_ZQ,
                                        dw, sqpart);
  k4a_scalar<<<1, 256, 0, stream>>>(ecs, clus, sqpart, csb, out);
  k4b_emb<<<256, 256, 0, stream>>>(emaw, dw, csb, out);
}

// Round 9
// 257.610 us; speedup vs baseline: 2.0084x; 1.0246x over previous
//
#include <hip/hip_runtime.h>
#include <hip/hip_bf16.h>
#include <math.h>

#define N_ROWS   131072   // 8*16384
#define DIMS     64
#define NCODES   1024
#define DECAY    0.99f
#define EPSF     1e-5f
#define BAND     2e-3f    // approx-gap band; eps_approx ~2e-4, 5x margin

// d_out layout (float32 elements)
#define OFF_ZQ    0
#define OFF_IDX   8388608
#define OFF_LOSS  8519680
#define OFF_PERP  8519681
#define OFF_EMB   8519682
#define OFF_ECS   8585218
#define OFF_EMAW  8586242

typedef unsigned int uint;
typedef short bf16x8 __attribute__((ext_vector_type(8)));
typedef float f32x4  __attribute__((ext_vector_type(4)));

__device__ __forceinline__ unsigned short bf16_rne(float f) {
  uint u = __float_as_uint(f);
  uint r = u + 0x7fffu + ((u >> 16) & 1u);
  return (unsigned short)(r >> 16);
}
__device__ __forceinline__ float bf16_f32(unsigned short h) {
  return __uint_as_float(((uint)h) << 16);
}

// numpy pairwise_sum base case (n=64): 8 strided accumulators, tree combine.
__device__ __forceinline__ float np_pairwise64_sq(const float* v) {
#pragma clang fp contract(off)
  float r[8];
#pragma unroll
  for (int j = 0; j < 8; ++j) r[j] = v[j] * v[j];
#pragma unroll
  for (int i = 8; i < 64; i += 8)
#pragma unroll
    for (int j = 0; j < 8; ++j) r[j] += v[i + j] * v[i + j];
  return ((r[0] + r[1]) + (r[2] + r[3])) + ((r[4] + r[5]) + (r[6] + r[7]));
}

// ---------------- K0m: merged init + pack (grid 64) ------------------------
// Block T: packs code-tile T into bf16 hi/mid B-fragments (all 256 threads),
// threads 0-15 compute np-exact ee for codes T*16+0..15, threads 16-31 zero
// cluster[T*16+...], block 0 zeroes cnt.
__global__ __launch_bounds__(256) void k0m(const float* __restrict__ emb,
                                           float* __restrict__ ee,
                                           uint* __restrict__ cluster,
                                           uint* __restrict__ cnt,
                                           bf16x8* __restrict__ bsplit) {
  int T = blockIdx.x;
  int t = threadIdx.x;
  int l = t & 63;
  int slot = t >> 6;                   // 0..3 = (ktile<<1)|split
  int ktile = slot >> 1, split = slot & 1;
  int code = T * 16 + (l & 15);
  int k0 = ktile * 32 + ((l >> 4) << 3);
  const float* ep = emb + (size_t)code * DIMS + k0;
  float4 fa = *(const float4*)ep;
  float4 fb = *(const float4*)(ep + 4);
  float fs[8] = {fa.x, fa.y, fa.z, fa.w, fb.x, fb.y, fb.z, fb.w};
  bf16x8 v;
#pragma unroll
  for (int i = 0; i < 8; ++i) {
    unsigned short h = bf16_rne(fs[i]);
    if (split == 0) v[i] = (short)h;
    else            v[i] = (short)bf16_rne(fs[i] - bf16_f32(h));
  }
  bsplit[(size_t)((T * 2 + ktile) * 2 + split) * 64 + l] = v;

  if (t < 16) {
    int c = T * 16 + t;
    float ev[DIMS];
    const float4* e4 = (const float4*)(emb + (size_t)c * DIMS);
#pragma unroll
    for (int i = 0; i < 16; ++i) {
      float4 w = e4[i];
      ev[4*i] = w.x; ev[4*i+1] = w.y; ev[4*i+2] = w.z; ev[4*i+3] = w.w;
    }
    ee[c] = np_pairwise64_sq(ev);
  } else if (t < 32) {
    cluster[T * 16 + (t - 16)] = 0u;
  }
  if (T == 0 && t == 32) *cnt = 0u;
}

// ---------------- K1: MFMA approx argmin, 4 row-tiles per wave -------------
// M-blocking: each wave owns 64 rows (4 tiles of 16); per loaded B fragment
// set (4 VMEM, L2-hot), 4x6 MFMA -> L2 bsplit traffic 2GB -> 512MB (the
// round-8 bottleneck). Per-element math, scan order, tie semantics, and the
// 16-lane reduce are VERBATIM from the round-7/8-validated kernel.
// Epilogue also does cluster counting (kc_count fused); k2 fixes deltas.
__global__ __launch_bounds__(256, 2) void k1_mfma(const float* __restrict__ z,
                                                  const bf16x8* __restrict__ bsplit,
                                                  const float* __restrict__ ee,
                                                  int* __restrict__ idx_out,
                                                  float* __restrict__ idx_f_out,
                                                  uint* __restrict__ cluster,
                                                  uint* __restrict__ cnt,
                                                  uint* __restrict__ list) {
  int l = threadIdx.x & 63;
  int w = __builtin_amdgcn_readfirstlane(threadIdx.x >> 6);
  int wavebase = blockIdx.x * 256 + w * 64;
  int kq = (l >> 4) << 3;              // 0,8,16,24
  int col = l & 15;

  // A fragments for 4 row-tiles: z rows split into bf16 hi/mid, same
  // (l,i)->k map as B (sigma-consistent).
  bf16x8 ahi[4][2], ami[4][2];
#pragma unroll
  for (int r = 0; r < 4; ++r) {
    int arow = wavebase + r * 16 + (l & 15);
#pragma unroll
    for (int t = 0; t < 2; ++t) {
      const float* zp = z + (size_t)arow * DIMS + t * 32 + kq;
      float4 fa = *(const float4*)zp;
      float4 fb = *(const float4*)(zp + 4);
      float fs[8] = {fa.x, fa.y, fa.z, fa.w, fb.x, fb.y, fb.z, fb.w};
#pragma unroll
      for (int i = 0; i < 8; ++i) {
        unsigned short h = bf16_rne(fs[i]);
        ahi[r][t][i] = (short)h;
        ami[r][t][i] = (short)bf16_rne(fs[i] - bf16_f32(h));
      }
    }
  }

  float best[4][4], second[4][4];
  int   bidx[4][4];
#pragma unroll
  for (int r = 0; r < 4; ++r)
#pragma unroll
    for (int j = 0; j < 4; ++j) {
      best[r][j] = 3.4e38f; second[r][j] = 3.4e38f; bidx[r][j] = 0;
    }

  for (int T = 0; T < 64; ++T) {
    const bf16x8* bp = bsplit + (size_t)(T * 4) * 64 + l;
    bf16x8 bhi0 = bp[0];          // (T,kt0,hi)
    bf16x8 bmi0 = bp[64];         // (T,kt0,mid)
    bf16x8 bhi1 = bp[128];        // (T,kt1,hi)
    bf16x8 bmi1 = bp[192];        // (T,kt1,mid)
    int code = T * 16 + col;
    float eeT = ee[code];
#pragma unroll
    for (int r = 0; r < 4; ++r) {
      f32x4 acc = {0.f, 0.f, 0.f, 0.f};
      acc = __builtin_amdgcn_mfma_f32_16x16x32_bf16(ahi[r][0], bhi0, acc, 0, 0, 0);
      acc = __builtin_amdgcn_mfma_f32_16x16x32_bf16(ahi[r][1], bhi1, acc, 0, 0, 0);
      acc = __builtin_amdgcn_mfma_f32_16x16x32_bf16(ahi[r][0], bmi0, acc, 0, 0, 0);
      acc = __builtin_amdgcn_mfma_f32_16x16x32_bf16(ahi[r][1], bmi1, acc, 0, 0, 0);
      acc = __builtin_amdgcn_mfma_f32_16x16x32_bf16(ami[r][0], bhi0, acc, 0, 0, 0);
      acc = __builtin_amdgcn_mfma_f32_16x16x32_bf16(ami[r][1], bhi1, acc, 0, 0, 0);
#pragma unroll
      for (int j = 0; j < 4; ++j) {
        float s = fmaf(-2.0f, acc[j], eeT);
        bool lt = s < best[r][j];
        second[r][j] = lt ? best[r][j] : fminf(second[r][j], s);
        best[r][j]   = lt ? s : best[r][j];
        bidx[r][j]   = lt ? code : bidx[r][j];
      }
    }
  }

  // reduce (best, second, idx) across the 16 lanes sharing l>>4 — verbatim
#pragma unroll
  for (int m = 1; m < 16; m <<= 1) {
#pragma unroll
    for (int r = 0; r < 4; ++r)
#pragma unroll
      for (int j = 0; j < 4; ++j) {
        float ob = __shfl_xor(best[r][j], m, 64);
        float os = __shfl_xor(second[r][j], m, 64);
        int   oi = __shfl_xor(bidx[r][j], m, 64);
        if (ob < best[r][j]) {
          second[r][j] = fminf(os, best[r][j]);
          best[r][j] = ob; bidx[r][j] = oi;
        } else if (ob == best[r][j]) {
          bidx[r][j] = min(bidx[r][j], oi);
          second[r][j] = fminf(second[r][j], fminf(os, ob));  // dup min -> gap 0
        } else {
          second[r][j] = fminf(second[r][j], ob);
        }
      }
  }

  if (col == 0) {
#pragma unroll
    for (int r = 0; r < 4; ++r)
#pragma unroll
      for (int j = 0; j < 4; ++j) {
        int row = wavebase + r * 16 + ((l >> 4) << 2) + j;
        idx_out[row] = bidx[r][j];
        idx_f_out[row] = (float)bidx[r][j];
        atomicAdd(&cluster[bidx[r][j]], 1u);
        if (second[r][j] - best[r][j] < BAND) {
          uint p = atomicAdd(cnt, 1u);
          list[p] = (uint)row;
        }
      }
  }
}

// ---------------- K2: exact recheck of near-tie rows (numpy-f32 bit-exact) --
// Also fixes cluster counts for rows whose index changes.
__global__ __launch_bounds__(256) void k2_recheck(const float* __restrict__ z,
                                                  const float* __restrict__ emb,
                                                  const float* __restrict__ ee,
                                                  const uint* __restrict__ cnt,
                                                  const uint* __restrict__ list,
                                                  int* __restrict__ idx_out,
                                                  float* __restrict__ idx_f_out,
                                                  uint* __restrict__ cluster) {
#pragma clang fp contract(off)
  __shared__ float zrow[DIMS];
  __shared__ float rv[256];
  __shared__ int   ri[256];
  int t = threadIdx.x;
  uint n = *cnt;
  for (uint i = blockIdx.x; i < n; i += gridDim.x) {
    uint row = list[i];
    __syncthreads();
    if (t < 16)
      ((float4*)zrow)[t] = ((const float4*)(z + (size_t)row * DIMS))[t];
    __syncthreads();
    float zz = np_pairwise64_sq(zrow);
    float best = 3.4e38f; int bi = 0;
#pragma unroll
    for (int k4 = 0; k4 < 4; ++k4) {
      int c = t * 4 + k4;                      // ascending codes per thread
      const float* e = emb + (size_t)c * DIMS;
      float a = 0.f;
      for (int k = 0; k < DIMS; ++k) a = fmaf(zrow[k], e[k], a);
      float d = fmaf(-2.0f, a, zz + ee[c]);
      if (d < best) { best = d; bi = c; }
    }
    rv[t] = best; ri[t] = bi;
    __syncthreads();
    for (int s = 128; s > 0; s >>= 1) {
      if (t < s) {
        float ov = rv[t + s]; int oi = ri[t + s];
        if (ov < rv[t] || (ov == rv[t] && oi < ri[t])) { rv[t] = ov; ri[t] = oi; }
      }
      __syncthreads();
    }
    if (t == 0) {
      int old = idx_out[row];
      if (ri[0] != old) {
        atomicSub(&cluster[old], 1u);
        atomicAdd(&cluster[ri[0]], 1u);
        idx_out[row] = ri[0];
        idx_f_out[row] = (float)ri[0];
      }
    }
  }
}

// ---------------- K3b: exclusive prefix over counts (1 block) --------------
__global__ __launch_bounds__(256) void k3b_prefix(const uint* __restrict__ cluster,
                                                  uint* __restrict__ starts,
                                                  uint* __restrict__ cursor) {
  __shared__ uint a[256], b[256];
  int t = threadIdx.x;
  uint c0 = cluster[t*4+0], c1 = cluster[t*4+1], c2 = cluster[t*4+2], c3 = cluster[t*4+3];
  uint s = c0 + c1 + c2 + c3;
  a[t] = s;
  __syncthreads();
  uint* src = a; uint* dst = b;
  for (int off = 1; off < 256; off <<= 1) {
    dst[t] = src[t] + ((t >= off) ? src[t - off] : 0u);
    __syncthreads();
    uint* tmp = src; src = dst; dst = tmp;
  }
  uint base = (t > 0) ? src[t-1] : 0u;
  uint p0 = base, p1 = p0 + c0, p2 = p1 + c1, p3 = p2 + c2;
  starts[t*4+0] = p0; starts[t*4+1] = p1; starts[t*4+2] = p2; starts[t*4+3] = p3;
  cursor[t*4+0] = p0; cursor[t*4+1] = p1; cursor[t*4+2] = p2; cursor[t*4+3] = p3;
  if (t == 255) starts[NCODES] = src[255];
}

// ---------------- K3c: scatter row ids into code buckets -------------------
__global__ __launch_bounds__(256) void k3c_scatter(const int* __restrict__ idx,
                                                   uint* __restrict__ cursor,
                                                   uint* __restrict__ rowids) {
  int row = blockIdx.x * 256 + threadIdx.x;
  int code = idx[row];
  uint pos = atomicAdd(&cursor[code], 1u);
  rowids[pos] = (uint)row;
}

// ---------------- K3d: fused per-code pass: zq + loss + dw -----------------
__global__ __launch_bounds__(256) void k3d_fused(const float* __restrict__ z,
                                                 const float* __restrict__ emb,
                                                 const uint* __restrict__ starts,
                                                 const uint* __restrict__ rowids,
                                                 float* __restrict__ out_zq,
                                                 float* __restrict__ dw,
                                                 double* __restrict__ sqpart) {
  __shared__ float  accf[4][64];
  __shared__ double accd[4][64];
  int code = blockIdx.x;
  int lane = threadIdx.x & 63, w = threadIdx.x >> 6;
  uint s0 = starts[code], s1 = starts[code + 1];
  float ev = emb[code * DIMS + lane];
  float fs = 0.f;
  double ds = 0.0;
  for (uint i = s0 + (uint)w; i < s1; i += 4) {
    uint r = rowids[i];                       // wave-uniform -> s_load
    float zv = z[(size_t)r * DIMS + lane];    // 256B coalesced per wave
    float d = ev - zv;
    float o = zv + d;                         // z_q_st, op-for-op as before
    out_zq[(size_t)r * DIMS + lane] = o;
    fs += zv;
    ds += (double)(d * d);
  }
  accf[w][lane] = fs; accd[w][lane] = ds;
  __syncthreads();
  if (threadIdx.x < 64) {
    float v = (accf[0][threadIdx.x] + accf[1][threadIdx.x])
            + (accf[2][threadIdx.x] + accf[3][threadIdx.x]);
    dw[code * DIMS + threadIdx.x] = v;
    double sd = (accd[0][threadIdx.x] + accd[1][threadIdx.x])
              + (accd[2][threadIdx.x] + accd[3][threadIdx.x]);
#pragma unroll
    for (int o2 = 32; o2 > 0; o2 >>= 1) sd += __shfl_down(sd, o2, 64);
    if (threadIdx.x == 0) sqpart[code] = sd;
  }
}

// ---------------- K4a: serial finalize (1 block) ---------------------------
__global__ __launch_bounds__(256) void k4a_scalar(const float* __restrict__ ecs_in,
                                                  const uint* __restrict__ cluster,
                                                  const double* __restrict__ sqpart,
                                                  float* __restrict__ csb,
                                                  float* __restrict__ out) {
  __shared__ double red[256];
  int t = threadIdx.x;

  double nloc = 0.0, aloc = 0.0, bloc = 0.0, sloc = 0.0;
  for (int c = t; c < NCODES; c += 256) {
    float cntf = (float)cluster[c];
    float ne = ecs_in[c] * DECAY + (1.0f - DECAY) * cntf;
    out[OFF_ECS + c] = ne;
    nloc += (double)ne;
    double p = (double)cntf / (double)N_ROWS;
    double pc = p < 1e-10 ? 1e-10 : p;
    bloc += pc;
    aloc += pc * log(pc);
    sloc += sqpart[c];
  }

  red[t] = nloc; __syncthreads();
  for (int s = 128; s > 0; s >>= 1) { if (t < s) red[t] += red[t + s]; __syncthreads(); }
  double n = red[0]; __syncthreads();

  red[t] = bloc; __syncthreads();
  for (int s = 128; s > 0; s >>= 1) { if (t < s) red[t] += red[t + s]; __syncthreads(); }
  double B = red[0]; __syncthreads();

  red[t] = aloc; __syncthreads();
  for (int s = 128; s > 0; s >>= 1) { if (t < s) red[t] += red[t + s]; __syncthreads(); }
  double A = red[0]; __syncthreads();

  red[t] = sloc; __syncthreads();
  for (int s = 128; s > 0; s >>= 1) { if (t < s) red[t] += red[t + s]; __syncthreads(); }
  double S = red[0]; __syncthreads();

  if (t == 0) {
    double ent = -(A / B - log(B));
    out[OFF_PERP] = (float)exp(ent);
    double M = S / (double)((size_t)N_ROWS * DIMS);
    out[OFF_LOSS] = (float)(1.5 * M);   // 0.5*commitment + codebook, both = M
  }

  float nf = (float)n;
  for (int c = t; c < NCODES; c += 256) {
    float ne = out[OFF_ECS + c];
    float cs = ((ne + EPSF) / (nf + (float)NCODES * EPSF)) * nf;
    csb[c] = cs < 0.01f ? 0.01f : cs;
  }
}

// ---------------- K4b: parallel finalize: ema_w + embedding ----------------
__global__ __launch_bounds__(256) void k4b_emb(const float* __restrict__ emaw_in,
                                               const float* __restrict__ dw,
                                               const float* __restrict__ csb,
                                               float* __restrict__ out) {
  int i = blockIdx.x * 256 + threadIdx.x;
  int c = i >> 6;
  float nw = emaw_in[i] * DECAY + (1.0f - DECAY) * dw[i];
  out[OFF_EMAW + i] = nw;
  out[OFF_EMB + i] = nw / csb[c];
}

// ---------------- host ----------------
extern "C" void kernel_launch(void* const* d_in, const int* in_sizes, int n_in,
                              void* d_out, int out_size, void* d_ws, size_t ws_size,
                              hipStream_t stream) {
  const float* z    = (const float*)d_in[0];
  const float* emb  = (const float*)d_in[1];
  const float* ecs  = (const float*)d_in[2];
  const float* emaw = (const float*)d_in[3];
  float* out = (float*)d_out;

  char* ws = (char*)d_ws;
  uint*   cnt    = (uint*)   (ws + 0);          // 16 B
  int*    idxw   = (int*)    (ws + 16);         // 512 KB
  uint*   clus   = (uint*)   (ws + 524304);     // 4 KB
  float*  dw     = (float*)  (ws + 528416);     // 256 KB
  float*  ee     = (float*)  (ws + 790560);     // 4 KB
  float*  csb    = (float*)  (ws + 794656);     // 4 KB
  uint*   starts = (uint*)   (ws + 798752);     // 8 KB
  uint*   cursor = (uint*)   (ws + 806944);     // 4 KB
  uint*   rowids = (uint*)   (ws + 811040);     // 512 KB
  bf16x8* bsplit = (bf16x8*) (ws + 1335328);    // 256 KB
  uint*   rlist  = (uint*)   (ws + 1597472);    // 512 KB
  // sqpart overlaps rlist: rlist dead after k2; sqpart written in k3d.
  double* sqpart = (double*) (ws + 1597472);

  k0m<<<64, 256, 0, stream>>>(emb, ee, clus, cnt, bsplit);
  k1_mfma<<<N_ROWS / 256, 256, 0, stream>>>(z, bsplit, ee, idxw, out + OFF_IDX,
                                            clus, cnt, rlist);
  k2_recheck<<<1024, 256, 0, stream>>>(z, emb, ee, cnt, rlist, idxw,
                                       out + OFF_IDX, clus);
  k3b_prefix<<<1, 256, 0, stream>>>(clus, starts, cursor);
  k3c_scatter<<<N_ROWS / 256, 256, 0, stream>>>(idxw, cursor, rowids);
  k3d_fused<<<NCODES, 256, 0, stream>>>(z, emb, starts, rowids, out + OFF_ZQ,
                                        dw, sqpart);
  k4a_scalar<<<1, 256, 0, stream>>>(ecs, clus, sqpart, csb, out);
  k4b_emb<<<256, 256, 0, stream>>>(emaw, dw, csb, out);
}

// Round 10
// 247.773 us; speedup vs baseline: 2.0881x; 1.0397x over previous
//
#include <hip/hip_runtime.h>
#include <hip/hip_bf16.h>
#include <math.h>

#define N_ROWS   131072   // 8*16384
#define DIMS     64
#define NCODES   1024
#define DECAY    0.99f
#define EPSF     1e-5f
#define BAND     2e-3f    // approx-gap band; eps_approx ~2e-4, 5x margin

// d_out layout (float32 elements)
#define OFF_ZQ    0
#define OFF_IDX   8388608
#define OFF_LOSS  8519680
#define OFF_PERP  8519681
#define OFF_EMB   8519682
#define OFF_ECS   8585218
#define OFF_EMAW  8586242

typedef unsigned int uint;
typedef short bf16x8 __attribute__((ext_vector_type(8)));
typedef float f32x4  __attribute__((ext_vector_type(4)));

__device__ __forceinline__ unsigned short bf16_rne(float f) {
  uint u = __float_as_uint(f);
  uint r = u + 0x7fffu + ((u >> 16) & 1u);
  return (unsigned short)(r >> 16);
}
__device__ __forceinline__ float bf16_f32(unsigned short h) {
  return __uint_as_float(((uint)h) << 16);
}

// numpy pairwise_sum base case (n=64): 8 strided accumulators, tree combine.
__device__ __forceinline__ float np_pairwise64_sq(const float* v) {
#pragma clang fp contract(off)
  float r[8];
#pragma unroll
  for (int j = 0; j < 8; ++j) r[j] = v[j] * v[j];
#pragma unroll
  for (int i = 8; i < 64; i += 8)
#pragma unroll
    for (int j = 0; j < 8; ++j) r[j] += v[i + j] * v[i + j];
  return ((r[0] + r[1]) + (r[2] + r[3])) + ((r[4] + r[5]) + (r[6] + r[7]));
}

// ---------------- K0m: merged init + pack (grid 64) ------------------------
__global__ __launch_bounds__(256) void k0m(const float* __restrict__ emb,
                                           float* __restrict__ ee,
                                           uint* __restrict__ cluster,
                                           uint* __restrict__ cnt,
                                           bf16x8* __restrict__ bsplit) {
  int T = blockIdx.x;
  int t = threadIdx.x;
  int l = t & 63;
  int slot = t >> 6;                   // 0..3 = (ktile<<1)|split
  int ktile = slot >> 1, split = slot & 1;
  int code = T * 16 + (l & 15);
  int k0 = ktile * 32 + ((l >> 4) << 3);
  const float* ep = emb + (size_t)code * DIMS + k0;
  float4 fa = *(const float4*)ep;
  float4 fb = *(const float4*)(ep + 4);
  float fs[8] = {fa.x, fa.y, fa.z, fa.w, fb.x, fb.y, fb.z, fb.w};
  bf16x8 v;
#pragma unroll
  for (int i = 0; i < 8; ++i) {
    unsigned short h = bf16_rne(fs[i]);
    if (split == 0) v[i] = (short)h;
    else            v[i] = (short)bf16_rne(fs[i] - bf16_f32(h));
  }
  bsplit[(size_t)((T * 2 + ktile) * 2 + split) * 64 + l] = v;

  if (t < 16) {
    int c = T * 16 + t;
    float ev[DIMS];
    const float4* e4 = (const float4*)(emb + (size_t)c * DIMS);
#pragma unroll
    for (int i = 0; i < 16; ++i) {
      float4 w = e4[i];
      ev[4*i] = w.x; ev[4*i+1] = w.y; ev[4*i+2] = w.z; ev[4*i+3] = w.w;
    }
    ee[c] = np_pairwise64_sq(ev);
  } else if (t < 32) {
    cluster[T * 16 + (t - 16)] = 0u;
  }
  if (T == 0 && t == 32) *cnt = 0u;
}

// ---------------- K1: MFMA approx argmin, 2 row-tiles per wave -------------
// R=2 M-blocking, hand-separated register state (round-9 lesson: an r-indexed
// array inside the unrollable-refused T-loop went to scratch -> WRITE_SIZE
// +4MB, occupancy 18%). Two explicit tile copies A/B of the round-8-proven
// code pattern; B-fragment L2 traffic 2GB -> 1GB. Per-element math, scan
// order, tie semantics VERBATIM.
#define TRACK(ACC, BEST, SEC, IDX) \
  _Pragma("unroll") \
  for (int j = 0; j < 4; ++j) { \
    float s = fmaf(-2.0f, ACC[j], eeT); \
    bool lt = s < BEST[j]; \
    SEC[j]  = lt ? BEST[j] : fminf(SEC[j], s); \
    BEST[j] = lt ? s : BEST[j]; \
    IDX[j]  = lt ? code : IDX[j]; \
  }

#define REDUCE16(BEST, SEC, IDX) \
  _Pragma("unroll") \
  for (int m = 1; m < 16; m <<= 1) { \
    _Pragma("unroll") \
    for (int j = 0; j < 4; ++j) { \
      float ob = __shfl_xor(BEST[j], m, 64); \
      float os = __shfl_xor(SEC[j], m, 64); \
      int   oi = __shfl_xor(IDX[j], m, 64); \
      if (ob < BEST[j]) { \
        SEC[j] = fminf(os, BEST[j]); \
        BEST[j] = ob; IDX[j] = oi; \
      } else if (ob == BEST[j]) { \
        IDX[j] = min(IDX[j], oi); \
        SEC[j] = fminf(SEC[j], fminf(os, ob)); \
      } else { \
        SEC[j] = fminf(SEC[j], ob); \
      } \
    } \
  }

#define EMIT(BEST, SEC, IDX, RBASE) \
  _Pragma("unroll") \
  for (int j = 0; j < 4; ++j) { \
    int row = (RBASE) + ((l >> 4) << 2) + j; \
    idx_out[row] = IDX[j]; \
    idx_f_out[row] = (float)IDX[j]; \
    atomicAdd(&cluster[IDX[j]], 1u); \
    if (SEC[j] - BEST[j] < BAND) { \
      uint p = atomicAdd(cnt, 1u); \
      list[p] = (uint)row; \
    } \
  }

__global__ __launch_bounds__(256) void k1_mfma(const float* __restrict__ z,
                                               const bf16x8* __restrict__ bsplit,
                                               const float* __restrict__ ee,
                                               int* __restrict__ idx_out,
                                               float* __restrict__ idx_f_out,
                                               uint* __restrict__ cluster,
                                               uint* __restrict__ cnt,
                                               uint* __restrict__ list) {
  int l = threadIdx.x & 63;
  int w = __builtin_amdgcn_readfirstlane(threadIdx.x >> 6);
  int wavebase = blockIdx.x * 128 + w * 32;   // grid 1024; wave owns 32 rows
  int kq = (l >> 4) << 3;                     // 0,8,16,24
  int col = l & 15;

  // A fragments, two row-tiles, named sets (no runtime-indexed outer dim)
  bf16x8 ahiA[2], amiA[2], ahiB[2], amiB[2];
  {
    int arow = wavebase + (l & 15);
#pragma unroll
    for (int t = 0; t < 2; ++t) {
      const float* zp = z + (size_t)arow * DIMS + t * 32 + kq;
      float4 fa = *(const float4*)zp;
      float4 fb = *(const float4*)(zp + 4);
      float fs[8] = {fa.x, fa.y, fa.z, fa.w, fb.x, fb.y, fb.z, fb.w};
#pragma unroll
      for (int i = 0; i < 8; ++i) {
        unsigned short h = bf16_rne(fs[i]);
        ahiA[t][i] = (short)h;
        amiA[t][i] = (short)bf16_rne(fs[i] - bf16_f32(h));
      }
    }
  }
  {
    int arow = wavebase + 16 + (l & 15);
#pragma unroll
    for (int t = 0; t < 2; ++t) {
      const float* zp = z + (size_t)arow * DIMS + t * 32 + kq;
      float4 fa = *(const float4*)zp;
      float4 fb = *(const float4*)(zp + 4);
      float fs[8] = {fa.x, fa.y, fa.z, fa.w, fb.x, fb.y, fb.z, fb.w};
#pragma unroll
      for (int i = 0; i < 8; ++i) {
        unsigned short h = bf16_rne(fs[i]);
        ahiB[t][i] = (short)h;
        amiB[t][i] = (short)bf16_rne(fs[i] - bf16_f32(h));
      }
    }
  }

  float bestA[4]  = {3.4e38f, 3.4e38f, 3.4e38f, 3.4e38f};
  float secA[4]   = {3.4e38f, 3.4e38f, 3.4e38f, 3.4e38f};
  int   idxA[4]   = {0, 0, 0, 0};
  float bestB[4]  = {3.4e38f, 3.4e38f, 3.4e38f, 3.4e38f};
  float secB[4]   = {3.4e38f, 3.4e38f, 3.4e38f, 3.4e38f};
  int   idxB[4]   = {0, 0, 0, 0};

  for (int T = 0; T < 64; ++T) {
    const bf16x8* bp = bsplit + (size_t)(T * 4) * 64 + l;
    bf16x8 bhi0 = bp[0];          // (T,kt0,hi)
    bf16x8 bmi0 = bp[64];         // (T,kt0,mid)
    bf16x8 bhi1 = bp[128];        // (T,kt1,hi)
    bf16x8 bmi1 = bp[192];        // (T,kt1,mid)
    int code = T * 16 + col;
    float eeT = ee[code];

    f32x4 accA = {0.f, 0.f, 0.f, 0.f};
    accA = __builtin_amdgcn_mfma_f32_16x16x32_bf16(ahiA[0], bhi0, accA, 0, 0, 0);
    accA = __builtin_amdgcn_mfma_f32_16x16x32_bf16(ahiA[1], bhi1, accA, 0, 0, 0);
    accA = __builtin_amdgcn_mfma_f32_16x16x32_bf16(ahiA[0], bmi0, accA, 0, 0, 0);
    accA = __builtin_amdgcn_mfma_f32_16x16x32_bf16(ahiA[1], bmi1, accA, 0, 0, 0);
    accA = __builtin_amdgcn_mfma_f32_16x16x32_bf16(amiA[0], bhi0, accA, 0, 0, 0);
    accA = __builtin_amdgcn_mfma_f32_16x16x32_bf16(amiA[1], bhi1, accA, 0, 0, 0);
    TRACK(accA, bestA, secA, idxA)

    f32x4 accB = {0.f, 0.f, 0.f, 0.f};
    accB = __builtin_amdgcn_mfma_f32_16x16x32_bf16(ahiB[0], bhi0, accB, 0, 0, 0);
    accB = __builtin_amdgcn_mfma_f32_16x16x32_bf16(ahiB[1], bhi1, accB, 0, 0, 0);
    accB = __builtin_amdgcn_mfma_f32_16x16x32_bf16(ahiB[0], bmi0, accB, 0, 0, 0);
    accB = __builtin_amdgcn_mfma_f32_16x16x32_bf16(ahiB[1], bmi1, accB, 0, 0, 0);
    accB = __builtin_amdgcn_mfma_f32_16x16x32_bf16(amiB[0], bhi0, accB, 0, 0, 0);
    accB = __builtin_amdgcn_mfma_f32_16x16x32_bf16(amiB[1], bhi1, accB, 0, 0, 0);
    TRACK(accB, bestB, secB, idxB)
  }

  REDUCE16(bestA, secA, idxA)
  REDUCE16(bestB, secB, idxB)

  if (col == 0) {
    EMIT(bestA, secA, idxA, wavebase)
    EMIT(bestB, secB, idxB, wavebase + 16)
  }
}

// ---------------- K2: exact recheck of near-tie rows (numpy-f32 bit-exact) --
__global__ __launch_bounds__(256) void k2_recheck(const float* __restrict__ z,
                                                  const float* __restrict__ emb,
                                                  const float* __restrict__ ee,
                                                  const uint* __restrict__ cnt,
                                                  const uint* __restrict__ list,
                                                  int* __restrict__ idx_out,
                                                  float* __restrict__ idx_f_out,
                                                  uint* __restrict__ cluster) {
#pragma clang fp contract(off)
  __shared__ float zrow[DIMS];
  __shared__ float rv[256];
  __shared__ int   ri[256];
  int t = threadIdx.x;
  uint n = *cnt;
  for (uint i = blockIdx.x; i < n; i += gridDim.x) {
    uint row = list[i];
    __syncthreads();
    if (t < 16)
      ((float4*)zrow)[t] = ((const float4*)(z + (size_t)row * DIMS))[t];
    __syncthreads();
    float zz = np_pairwise64_sq(zrow);
    float best = 3.4e38f; int bi = 0;
#pragma unroll
    for (int k4 = 0; k4 < 4; ++k4) {
      int c = t * 4 + k4;                      // ascending codes per thread
      const float* e = emb + (size_t)c * DIMS;
      float a = 0.f;
      for (int k = 0; k < DIMS; ++k) a = fmaf(zrow[k], e[k], a);
      float d = fmaf(-2.0f, a, zz + ee[c]);
      if (d < best) { best = d; bi = c; }
    }
    rv[t] = best; ri[t] = bi;
    __syncthreads();
    for (int s = 128; s > 0; s >>= 1) {
      if (t < s) {
        float ov = rv[t + s]; int oi = ri[t + s];
        if (ov < rv[t] || (ov == rv[t] && oi < ri[t])) { rv[t] = ov; ri[t] = oi; }
      }
      __syncthreads();
    }
    if (t == 0) {
      int old = idx_out[row];
      if (ri[0] != old) {
        atomicSub(&cluster[old], 1u);
        atomicAdd(&cluster[ri[0]], 1u);
        idx_out[row] = ri[0];
        idx_f_out[row] = (float)ri[0];
      }
    }
  }
}

// ---------------- K3b: exclusive prefix over counts (1 block) --------------
__global__ __launch_bounds__(256) void k3b_prefix(const uint* __restrict__ cluster,
                                                  uint* __restrict__ starts,
                                                  uint* __restrict__ cursor) {
  __shared__ uint a[256], b[256];
  int t = threadIdx.x;
  uint c0 = cluster[t*4+0], c1 = cluster[t*4+1], c2 = cluster[t*4+2], c3 = cluster[t*4+3];
  uint s = c0 + c1 + c2 + c3;
  a[t] = s;
  __syncthreads();
  uint* src = a; uint* dst = b;
  for (int off = 1; off < 256; off <<= 1) {
    dst[t] = src[t] + ((t >= off) ? src[t - off] : 0u);
    __syncthreads();
    uint* tmp = src; src = dst; dst = tmp;
  }
  uint base = (t > 0) ? src[t-1] : 0u;
  uint p0 = base, p1 = p0 + c0, p2 = p1 + c1, p3 = p2 + c2;
  starts[t*4+0] = p0; starts[t*4+1] = p1; starts[t*4+2] = p2; starts[t*4+3] = p3;
  cursor[t*4+0] = p0; cursor[t*4+1] = p1; cursor[t*4+2] = p2; cursor[t*4+3] = p3;
  if (t == 255) starts[NCODES] = src[255];
}

// ---------------- K3c: scatter row ids into code buckets -------------------
__global__ __launch_bounds__(256) void k3c_scatter(const int* __restrict__ idx,
                                                   uint* __restrict__ cursor,
                                                   uint* __restrict__ rowids) {
  int row = blockIdx.x * 256 + threadIdx.x;
  int code = idx[row];
  uint pos = atomicAdd(&cursor[code], 1u);
  rowids[pos] = (uint)row;
}

// ---------------- K3d: fused per-code pass: zq + loss + dw -----------------
__global__ __launch_bounds__(256) void k3d_fused(const float* __restrict__ z,
                                                 const float* __restrict__ emb,
                                                 const uint* __restrict__ starts,
                                                 const uint* __restrict__ rowids,
                                                 float* __restrict__ out_zq,
                                                 float* __restrict__ dw,
                                                 double* __restrict__ sqpart) {
  __shared__ float  accf[4][64];
  __shared__ double accd[4][64];
  int code = blockIdx.x;
  int lane = threadIdx.x & 63, w = threadIdx.x >> 6;
  uint s0 = starts[code], s1 = starts[code + 1];
  float ev = emb[code * DIMS + lane];
  float fs = 0.f;
  double ds = 0.0;
  for (uint i = s0 + (uint)w; i < s1; i += 4) {
    uint r = rowids[i];                       // wave-uniform -> s_load
    float zv = z[(size_t)r * DIMS + lane];    // 256B coalesced per wave
    float d = ev - zv;
    float o = zv + d;                         // z_q_st, op-for-op as before
    out_zq[(size_t)r * DIMS + lane] = o;
    fs += zv;
    ds += (double)(d * d);
  }
  accf[w][lane] = fs; accd[w][lane] = ds;
  __syncthreads();
  if (threadIdx.x < 64) {
    float v = (accf[0][threadIdx.x] + accf[1][threadIdx.x])
            + (accf[2][threadIdx.x] + accf[3][threadIdx.x]);
    dw[code * DIMS + threadIdx.x] = v;
    double sd = (accd[0][threadIdx.x] + accd[1][threadIdx.x])
              + (accd[2][threadIdx.x] + accd[3][threadIdx.x]);
#pragma unroll
    for (int o2 = 32; o2 > 0; o2 >>= 1) sd += __shfl_down(sd, o2, 64);
    if (threadIdx.x == 0) sqpart[code] = sd;
  }
}

// ---------------- K4a: serial finalize (1 block) ---------------------------
__global__ __launch_bounds__(256) void k4a_scalar(const float* __restrict__ ecs_in,
                                                  const uint* __restrict__ cluster,
                                                  const double* __restrict__ sqpart,
                                                  float* __restrict__ csb,
                                                  float* __restrict__ out) {
  __shared__ double red[256];
  int t = threadIdx.x;

  double nloc = 0.0, aloc = 0.0, bloc = 0.0, sloc = 0.0;
  for (int c = t; c < NCODES; c += 256) {
    float cntf = (float)cluster[c];
    float ne = ecs_in[c] * DECAY + (1.0f - DECAY) * cntf;
    out[OFF_ECS + c] = ne;
    nloc += (double)ne;
    double p = (double)cntf / (double)N_ROWS;
    double pc = p < 1e-10 ? 1e-10 : p;
    bloc += pc;
    aloc += pc * log(pc);
    sloc += sqpart[c];
  }

  red[t] = nloc; __syncthreads();
  for (int s = 128; s > 0; s >>= 1) { if (t < s) red[t] += red[t + s]; __syncthreads(); }
  double n = red[0]; __syncthreads();

  red[t] = bloc; __syncthreads();
  for (int s = 128; s > 0; s >>= 1) { if (t < s) red[t] += red[t + s]; __syncthreads(); }
  double B = red[0]; __syncthreads();

  red[t] = aloc; __syncthreads();
  for (int s = 128; s > 0; s >>= 1) { if (t < s) red[t] += red[t + s]; __syncthreads(); }
  double A = red[0]; __syncthreads();

  red[t] = sloc; __syncthreads();
  for (int s = 128; s > 0; s >>= 1) { if (t < s) red[t] += red[t + s]; __syncthreads(); }
  double S = red[0]; __syncthreads();

  if (t == 0) {
    double ent = -(A / B - log(B));
    out[OFF_PERP] = (float)exp(ent);
    double M = S / (double)((size_t)N_ROWS * DIMS);
    out[OFF_LOSS] = (float)(1.5 * M);   // 0.5*commitment + codebook, both = M
  }

  float nf = (float)n;
  for (int c = t; c < NCODES; c += 256) {
    float ne = out[OFF_ECS + c];
    float cs = ((ne + EPSF) / (nf + (float)NCODES * EPSF)) * nf;
    csb[c] = cs < 0.01f ? 0.01f : cs;
  }
}

// ---------------- K4b: parallel finalize: ema_w + embedding ----------------
__global__ __launch_bounds__(256) void k4b_emb(const float* __restrict__ emaw_in,
                                               const float* __restrict__ dw,
                                               const float* __restrict__ csb,
                                               float* __restrict__ out) {
  int i = blockIdx.x * 256 + threadIdx.x;
  int c = i >> 6;
  float nw = emaw_in[i] * DECAY + (1.0f - DECAY) * dw[i];
  out[OFF_EMAW + i] = nw;
  out[OFF_EMB + i] = nw / csb[c];
}

// ---------------- host ----------------
extern "C" void kernel_launch(void* const* d_in, const int* in_sizes, int n_in,
                              void* d_out, int out_size, void* d_ws, size_t ws_size,
                              hipStream_t stream) {
  const float* z    = (const float*)d_in[0];
  const float* emb  = (const float*)d_in[1];
  const float* ecs  = (const float*)d_in[2];
  const float* emaw = (const float*)d_in[3];
  float* out = (float*)d_out;

  char* ws = (char*)d_ws;
  uint*   cnt    = (uint*)   (ws + 0);          // 16 B
  int*    idxw   = (int*)    (ws + 16);         // 512 KB
  uint*   clus   = (uint*)   (ws + 524304);     // 4 KB
  float*  dw     = (float*)  (ws + 528416);     // 256 KB
  float*  ee     = (float*)  (ws + 790560);     // 4 KB
  float*  csb    = (float*)  (ws + 794656);     // 4 KB
  uint*   starts = (uint*)   (ws + 798752);     // 8 KB
  uint*   cursor = (uint*)   (ws + 806944);     // 4 KB
  uint*   rowids = (uint*)   (ws + 811040);     // 512 KB
  bf16x8* bsplit = (bf16x8*) (ws + 1335328);    // 256 KB
  uint*   rlist  = (uint*)   (ws + 1597472);    // 512 KB
  // sqpart overlaps rlist: rlist dead after k2; sqpart written in k3d.
  double* sqpart = (double*) (ws + 1597472);

  k0m<<<64, 256, 0, stream>>>(emb, ee, clus, cnt, bsplit);
  k1_mfma<<<N_ROWS / 128, 256, 0, stream>>>(z, bsplit, ee, idxw, out + OFF_IDX,
                                            clus, cnt, rlist);
  k2_recheck<<<1024, 256, 0, stream>>>(z, emb, ee, cnt, rlist, idxw,
                                       out + OFF_IDX, clus);
  k3b_prefix<<<1, 256, 0, stream>>>(clus, starts, cursor);
  k3c_scatter<<<N_ROWS / 256, 256, 0, stream>>>(idxw, cursor, rowids);
  k3d_fused<<<NCODES, 256, 0, stream>>>(z, emb, starts, rowids, out + OFF_ZQ,
                                        dw, sqpart);
  k4a_scalar<<<1, 256, 0, stream>>>(ecs, clus, sqpart, csb, out);
  k4b_emb<<<256, 256, 0, stream>>>(emaw, dw, csb, out);
}

// Round 11
// 206.061 us; speedup vs baseline: 2.5108x; 1.2024x over previous
//
#include <hip/hip_runtime.h>
#include <hip/hip_bf16.h>
#include <math.h>

#define N_ROWS   131072   // 8*16384
#define DIMS     64
#define NCODES   1024
#define DECAY    0.99f
#define EPSF     1e-5f
#define BAND     2e-3f    // approx-gap band; eps_approx ~2e-4, 5x margin

// d_out layout (float32 elements)
#define OFF_ZQ    0
#define OFF_IDX   8388608
#define OFF_LOSS  8519680
#define OFF_PERP  8519681
#define OFF_EMB   8519682
#define OFF_ECS   8585218
#define OFF_EMAW  8586242

typedef unsigned int uint;
typedef short bf16x8 __attribute__((ext_vector_type(8)));
typedef float f32x4  __attribute__((ext_vector_type(4)));

__device__ __forceinline__ float atomic_add_f32(float* p, float v) {
  return __hip_atomic_fetch_add(p, v, __ATOMIC_RELAXED, __HIP_MEMORY_SCOPE_AGENT);
}

__device__ __forceinline__ unsigned short bf16_rne(float f) {
  uint u = __float_as_uint(f);
  uint r = u + 0x7fffu + ((u >> 16) & 1u);
  return (unsigned short)(r >> 16);
}
__device__ __forceinline__ float bf16_f32(unsigned short h) {
  return __uint_as_float(((uint)h) << 16);
}

// numpy pairwise_sum base case (n=64): 8 strided accumulators, tree combine.
__device__ __forceinline__ float np_pairwise64_sq(const float* v) {
#pragma clang fp contract(off)
  float r[8];
#pragma unroll
  for (int j = 0; j < 8; ++j) r[j] = v[j] * v[j];
#pragma unroll
  for (int i = 8; i < 64; i += 8)
#pragma unroll
    for (int j = 0; j < 8; ++j) r[j] += v[i + j] * v[i + j];
  return ((r[0] + r[1]) + (r[2] + r[3])) + ((r[4] + r[5]) + (r[6] + r[7]));
}

// ---------------- K0m: merged init + pack (grid 64) ------------------------
__global__ __launch_bounds__(256) void k0m(const float* __restrict__ emb,
                                           float* __restrict__ ee,
                                           uint* __restrict__ cluster,
                                           uint* __restrict__ cnt,
                                           bf16x8* __restrict__ bsplit,
                                           float* __restrict__ dw) {
  int T = blockIdx.x;
  int t = threadIdx.x;
  int gid = T * 256 + t;               // 16384 threads
  for (int i = gid; i < NCODES * DIMS; i += 16384) dw[i] = 0.0f;

  int l = t & 63;
  int slot = t >> 6;                   // 0..3 = (ktile<<1)|split
  int ktile = slot >> 1, split = slot & 1;
  int code = T * 16 + (l & 15);
  int k0 = ktile * 32 + ((l >> 4) << 3);
  const float* ep = emb + (size_t)code * DIMS + k0;
  float4 fa = *(const float4*)ep;
  float4 fb = *(const float4*)(ep + 4);
  float fs[8] = {fa.x, fa.y, fa.z, fa.w, fb.x, fb.y, fb.z, fb.w};
  bf16x8 v;
#pragma unroll
  for (int i = 0; i < 8; ++i) {
    unsigned short h = bf16_rne(fs[i]);
    if (split == 0) v[i] = (short)h;
    else            v[i] = (short)bf16_rne(fs[i] - bf16_f32(h));
  }
  bsplit[(size_t)((T * 2 + ktile) * 2 + split) * 64 + l] = v;

  if (t < 16) {
    int c = T * 16 + t;
    float ev[DIMS];
    const float4* e4 = (const float4*)(emb + (size_t)c * DIMS);
#pragma unroll
    for (int i = 0; i < 16; ++i) {
      float4 w = e4[i];
      ev[4*i] = w.x; ev[4*i+1] = w.y; ev[4*i+2] = w.z; ev[4*i+3] = w.w;
    }
    ee[c] = np_pairwise64_sq(ev);
  } else if (t < 32) {
    cluster[T * 16 + (t - 16)] = 0u;
  }
  if (T == 0 && t == 32) *cnt = 0u;
}

// ---------------- K1: MFMA approx argmin (round-8 R=1 structure) -----------
// Block = 4 waves; wave w owns 16 rows. 6 mfma per 16-code tile. s = ee -
// 2*dot (zz dropped: row-constant). best/second/idx tracking + 16-lane
// reduce VERBATIM from round-7/8-validated kernel. R=2/R=4 M-blocking both
// regressed (latency/occupancy-bound, not L2-BW-bound) -- keep R=1.
__global__ __launch_bounds__(256) void k1_mfma(const float* __restrict__ z,
                                               const bf16x8* __restrict__ bsplit,
                                               const float* __restrict__ ee,
                                               int* __restrict__ idx_out,
                                               float* __restrict__ idx_f_out,
                                               uint* __restrict__ cluster,
                                               uint* __restrict__ cnt,
                                               uint* __restrict__ list) {
  int l = threadIdx.x & 63;
  int w = threadIdx.x >> 6;
  int rowbase = blockIdx.x * 64 + w * 16;
  int arow = rowbase + (l & 15);
  int kq = (l >> 4) << 3;              // 0,8,16,24

  // A fragments: z row split into bf16 hi/mid, same (l,i)->k map as B
  bf16x8 ahi[2], ami[2];
#pragma unroll
  for (int t = 0; t < 2; ++t) {
    const float* zp = z + (size_t)arow * DIMS + t * 32 + kq;
    float4 fa = *(const float4*)zp;
    float4 fb = *(const float4*)(zp + 4);
    float fs[8] = {fa.x, fa.y, fa.z, fa.w, fb.x, fb.y, fb.z, fb.w};
#pragma unroll
    for (int i = 0; i < 8; ++i) {
      unsigned short h = bf16_rne(fs[i]);
      ahi[t][i] = (short)h;
      ami[t][i] = (short)bf16_rne(fs[i] - bf16_f32(h));
    }
  }

  float best[4]  = {3.4e38f, 3.4e38f, 3.4e38f, 3.4e38f};
  float second[4] = {3.4e38f, 3.4e38f, 3.4e38f, 3.4e38f};
  int   bidx[4] = {0, 0, 0, 0};
  int   col = l & 15;

#pragma unroll 2
  for (int T = 0; T < 64; ++T) {
    const bf16x8* bp = bsplit + (size_t)(T * 4) * 64 + l;
    bf16x8 bhi0 = bp[0];          // (T,kt0,hi)
    bf16x8 bmi0 = bp[64];         // (T,kt0,mid)
    bf16x8 bhi1 = bp[128];        // (T,kt1,hi)
    bf16x8 bmi1 = bp[192];        // (T,kt1,mid)
    f32x4 acc = {0.f, 0.f, 0.f, 0.f};
    acc = __builtin_amdgcn_mfma_f32_16x16x32_bf16(ahi[0], bhi0, acc, 0, 0, 0);
    acc = __builtin_amdgcn_mfma_f32_16x16x32_bf16(ahi[1], bhi1, acc, 0, 0, 0);
    acc = __builtin_amdgcn_mfma_f32_16x16x32_bf16(ahi[0], bmi0, acc, 0, 0, 0);
    acc = __builtin_amdgcn_mfma_f32_16x16x32_bf16(ahi[1], bmi1, acc, 0, 0, 0);
    acc = __builtin_amdgcn_mfma_f32_16x16x32_bf16(ami[0], bhi0, acc, 0, 0, 0);
    acc = __builtin_amdgcn_mfma_f32_16x16x32_bf16(ami[1], bhi1, acc, 0, 0, 0);

    int code = T * 16 + col;
    float eeT = ee[code];
#pragma unroll
    for (int j = 0; j < 4; ++j) {
      float s = fmaf(-2.0f, acc[j], eeT);
      bool lt = s < best[j];
      second[j] = lt ? best[j] : fminf(second[j], s);
      best[j]   = lt ? s : best[j];
      bidx[j]   = lt ? code : bidx[j];
    }
  }

  // reduce (best, second, idx) across the 16 lanes sharing l>>4
#pragma unroll
  for (int m = 1; m < 16; m <<= 1) {
#pragma unroll
    for (int j = 0; j < 4; ++j) {
      float ob = __shfl_xor(best[j], m, 64);
      float os = __shfl_xor(second[j], m, 64);
      int   oi = __shfl_xor(bidx[j], m, 64);
      if (ob < best[j]) {
        second[j] = fminf(os, best[j]);
        best[j] = ob; bidx[j] = oi;
      } else if (ob == best[j]) {
        bidx[j] = min(bidx[j], oi);
        second[j] = fminf(second[j], fminf(os, ob));  // dup min -> gap 0
      } else {
        second[j] = fminf(second[j], ob);
      }
    }
  }

  if (col == 0) {
#pragma unroll
    for (int j = 0; j < 4; ++j) {
      int r = rowbase + ((l >> 4) << 2) + j;
      idx_out[r] = bidx[j];
      idx_f_out[r] = (float)bidx[j];
      atomicAdd(&cluster[bidx[j]], 1u);
      if (second[j] - best[j] < BAND) {
        uint p = atomicAdd(cnt, 1u);
        list[p] = (uint)r;
      }
    }
  }
}

// ---------------- K2: exact recheck of near-tie rows (numpy-f32 bit-exact) --
__global__ __launch_bounds__(256) void k2_recheck(const float* __restrict__ z,
                                                  const float* __restrict__ emb,
                                                  const float* __restrict__ ee,
                                                  const uint* __restrict__ cnt,
                                                  const uint* __restrict__ list,
                                                  int* __restrict__ idx_out,
                                                  float* __restrict__ idx_f_out,
                                                  uint* __restrict__ cluster) {
#pragma clang fp contract(off)
  __shared__ float zrow[DIMS];
  __shared__ float rv[256];
  __shared__ int   ri[256];
  int t = threadIdx.x;
  uint n = *cnt;
  for (uint i = blockIdx.x; i < n; i += gridDim.x) {
    uint row = list[i];
    __syncthreads();
    if (t < 16)
      ((float4*)zrow)[t] = ((const float4*)(z + (size_t)row * DIMS))[t];
    __syncthreads();
    float zz = np_pairwise64_sq(zrow);
    float best = 3.4e38f; int bi = 0;
#pragma unroll
    for (int k4 = 0; k4 < 4; ++k4) {
      int c = t * 4 + k4;                      // ascending codes per thread
      const float* e = emb + (size_t)c * DIMS;
      float a = 0.f;
      for (int k = 0; k < DIMS; ++k) a = fmaf(zrow[k], e[k], a);
      float d = fmaf(-2.0f, a, zz + ee[c]);
      if (d < best) { best = d; bi = c; }
    }
    rv[t] = best; ri[t] = bi;
    __syncthreads();
    for (int s = 128; s > 0; s >>= 1) {
      if (t < s) {
        float ov = rv[t + s]; int oi = ri[t + s];
        if (ov < rv[t] || (ov == rv[t] && oi < ri[t])) { rv[t] = ov; ri[t] = oi; }
      }
      __syncthreads();
    }
    if (t == 0) {
      int old = idx_out[row];
      if (ri[0] != old) {
        atomicSub(&cluster[old], 1u);
        atomicAdd(&cluster[ri[0]], 1u);
        idx_out[row] = ri[0];
        idx_f_out[row] = (float)ri[0];
      }
    }
  }
}

// ---------------- K3b: exclusive prefix over counts (1 block) --------------
__global__ __launch_bounds__(256) void k3b_prefix(const uint* __restrict__ cluster,
                                                  uint* __restrict__ starts,
                                                  uint* __restrict__ cursor) {
  __shared__ uint a[256], b[256];
  int t = threadIdx.x;
  uint c0 = cluster[t*4+0], c1 = cluster[t*4+1], c2 = cluster[t*4+2], c3 = cluster[t*4+3];
  uint s = c0 + c1 + c2 + c3;
  a[t] = s;
  __syncthreads();
  uint* src = a; uint* dst = b;
  for (int off = 1; off < 256; off <<= 1) {
    dst[t] = src[t] + ((t >= off) ? src[t - off] : 0u);
    __syncthreads();
    uint* tmp = src; src = dst; dst = tmp;
  }
  uint base = (t > 0) ? src[t-1] : 0u;
  uint p0 = base, p1 = p0 + c0, p2 = p1 + c1, p3 = p2 + c2;
  starts[t*4+0] = p0; starts[t*4+1] = p1; starts[t*4+2] = p2; starts[t*4+3] = p3;
  cursor[t*4+0] = p0; cursor[t*4+1] = p1; cursor[t*4+2] = p2; cursor[t*4+3] = p3;
  if (t == 255) starts[NCODES] = src[255];
}

// ---------------- K3c: scatter row ids + codes into sorted positions -------
__global__ __launch_bounds__(256) void k3c_scatter(const int* __restrict__ idx,
                                                   uint* __restrict__ cursor,
                                                   uint* __restrict__ rowids,
                                                   int* __restrict__ codes) {
  int row = blockIdx.x * 256 + threadIdx.x;
  int code = idx[row];
  uint pos = atomicAdd(&cursor[code], 1u);
  rowids[pos] = (uint)row;
  codes[pos] = code;
}

// ---------------- K3d: POSITION-balanced fused pass: zq + loss + dw --------
// Round-10 lesson: block-per-code serializes on the largest cluster (skewed
// winner distribution -> one block ~100us while 1023 idle). Now block = 128
// consecutive SORTED positions (wave = 32 positions, lane = dim); run-length
// accumulate dw, flush via f32 atomics on code change (~5K flushes total).
// zq formula op-for-op identical; loss f64 partial per block -> sqpart[b].
__global__ __launch_bounds__(256) void k3d_fused(const float* __restrict__ z,
                                                 const float* __restrict__ emb,
                                                 const uint* __restrict__ rowids,
                                                 const int* __restrict__ codes,
                                                 float* __restrict__ out_zq,
                                                 float* __restrict__ dw,
                                                 double* __restrict__ sqpart) {
  __shared__ double accd[4];
  int lane = threadIdx.x & 63, w = threadIdx.x >> 6;
  int base = blockIdx.x * 128 + w * 32;

  int cur = codes[base];                      // wave-uniform
  float acc = 0.f;
  double ds = 0.0;
  for (int i = 0; i < 32; ++i) {
    int p = base + i;
    uint r = rowids[p];                       // wave-uniform s_load
    int c = codes[p];                         // wave-uniform s_load
    if (c != cur) {                           // uniform branch
      atomic_add_f32(&dw[cur * DIMS + lane], acc);
      acc = 0.f; cur = c;
    }
    float zv = z[(size_t)r * DIMS + lane];    // 256B coalesced
    float ev = emb[c * DIMS + lane];          // L1/L2-hot
    float d = ev - zv;
    float o = zv + d;                         // z_q_st, op-for-op as before
    out_zq[(size_t)r * DIMS + lane] = o;
    acc += zv;
    ds += (double)(d * d);
  }
  atomic_add_f32(&dw[cur * DIMS + lane], acc);

  // block-reduce ds -> sqpart[blockIdx]
#pragma unroll
  for (int o2 = 32; o2 > 0; o2 >>= 1) ds += __shfl_down(ds, o2, 64);
  if (lane == 0) accd[w] = ds;
  __syncthreads();
  if (threadIdx.x == 0)
    sqpart[blockIdx.x] = (accd[0] + accd[1]) + (accd[2] + accd[3]);
}

// ---------------- K4a: serial finalize (1 block) ---------------------------
__global__ __launch_bounds__(256) void k4a_scalar(const float* __restrict__ ecs_in,
                                                  const uint* __restrict__ cluster,
                                                  const double* __restrict__ sqpart,
                                                  float* __restrict__ csb,
                                                  float* __restrict__ out) {
  __shared__ double red[256];
  int t = threadIdx.x;

  double nloc = 0.0, aloc = 0.0, bloc = 0.0, sloc = 0.0;
  for (int c = t; c < NCODES; c += 256) {
    float cntf = (float)cluster[c];
    float ne = ecs_in[c] * DECAY + (1.0f - DECAY) * cntf;
    out[OFF_ECS + c] = ne;
    nloc += (double)ne;
    double p = (double)cntf / (double)N_ROWS;
    double pc = p < 1e-10 ? 1e-10 : p;
    bloc += pc;
    aloc += pc * log(pc);
    sloc += sqpart[c];                        // 1024 block partials
  }

  red[t] = nloc; __syncthreads();
  for (int s = 128; s > 0; s >>= 1) { if (t < s) red[t] += red[t + s]; __syncthreads(); }
  double n = red[0]; __syncthreads();

  red[t] = bloc; __syncthreads();
  for (int s = 128; s > 0; s >>= 1) { if (t < s) red[t] += red[t + s]; __syncthreads(); }
  double B = red[0]; __syncthreads();

  red[t] = aloc; __syncthreads();
  for (int s = 128; s > 0; s >>= 1) { if (t < s) red[t] += red[t + s]; __syncthreads(); }
  double A = red[0]; __syncthreads();

  red[t] = sloc; __syncthreads();
  for (int s = 128; s > 0; s >>= 1) { if (t < s) red[t] += red[t + s]; __syncthreads(); }
  double S = red[0]; __syncthreads();

  if (t == 0) {
    double ent = -(A / B - log(B));
    out[OFF_PERP] = (float)exp(ent);
    double M = S / (double)((size_t)N_ROWS * DIMS);
    out[OFF_LOSS] = (float)(1.5 * M);   // 0.5*commitment + codebook, both = M
  }

  float nf = (float)n;
  for (int c = t; c < NCODES; c += 256) {
    float ne = out[OFF_ECS + c];
    float cs = ((ne + EPSF) / (nf + (float)NCODES * EPSF)) * nf;
    csb[c] = cs < 0.01f ? 0.01f : cs;
  }
}

// ---------------- K4b: parallel finalize: ema_w + embedding ----------------
__global__ __launch_bounds__(256) void k4b_emb(const float* __restrict__ emaw_in,
                                               const float* __restrict__ dw,
                                               const float* __restrict__ csb,
                                               float* __restrict__ out) {
  int i = blockIdx.x * 256 + threadIdx.x;
  int c = i >> 6;
  float nw = emaw_in[i] * DECAY + (1.0f - DECAY) * dw[i];
  out[OFF_EMAW + i] = nw;
  out[OFF_EMB + i] = nw / csb[c];
}

// ---------------- host ----------------
extern "C" void kernel_launch(void* const* d_in, const int* in_sizes, int n_in,
                              void* d_out, int out_size, void* d_ws, size_t ws_size,
                              hipStream_t stream) {
  const float* z    = (const float*)d_in[0];
  const float* emb  = (const float*)d_in[1];
  const float* ecs  = (const float*)d_in[2];
  const float* emaw = (const float*)d_in[3];
  float* out = (float*)d_out;

  char* ws = (char*)d_ws;
  uint*   cnt    = (uint*)   (ws + 0);          // 16 B
  int*    idxw   = (int*)    (ws + 16);         // 512 KB
  uint*   clus   = (uint*)   (ws + 524304);     // 4 KB
  float*  dw     = (float*)  (ws + 528416);     // 256 KB
  float*  ee     = (float*)  (ws + 790560);     // 4 KB
  float*  csb    = (float*)  (ws + 794656);     // 4 KB
  uint*   starts = (uint*)   (ws + 798752);     // 8 KB
  uint*   cursor = (uint*)   (ws + 806944);     // 4 KB
  uint*   rowids = (uint*)   (ws + 811040);     // 512 KB
  bf16x8* bsplit = (bf16x8*) (ws + 1335328);    // 256 KB
  uint*   rlist  = (uint*)   (ws + 1597472);    // 512 KB
  // sqpart overlaps rlist: rlist dead after k2; sqpart written in k3d.
  double* sqpart = (double*) (ws + 1597472);    // 8 KB (within rlist region)
  int*    codes  = (int*)    (ws + 2121760);    // 512 KB

  k0m<<<64, 256, 0, stream>>>(emb, ee, clus, cnt, bsplit, dw);
  k1_mfma<<<N_ROWS / 64, 256, 0, stream>>>(z, bsplit, ee, idxw, out + OFF_IDX,
                                           clus, cnt, rlist);
  k2_recheck<<<1024, 256, 0, stream>>>(z, emb, ee, cnt, rlist, idxw,
                                       out + OFF_IDX, clus);
  k3b_prefix<<<1, 256, 0, stream>>>(clus, starts, cursor);
  k3c_scatter<<<N_ROWS / 256, 256, 0, stream>>>(idxw, cursor, rowids, codes);
  k3d_fused<<<N_ROWS / 128, 256, 0, stream>>>(z, emb, rowids, codes,
                                              out + OFF_ZQ, dw, sqpart);
  k4a_scalar<<<1, 256, 0, stream>>>(ecs, clus, sqpart, csb, out);
  k4b_emb<<<256, 256, 0, stream>>>(emaw, dw, csb, out);
}

// Round 12
// 195.387 us; speedup vs baseline: 2.6480x; 1.0546x over previous
//
#include <hip/hip_runtime.h>
#include <hip/hip_bf16.h>
#include <math.h>

#define N_ROWS   131072   // 8*16384
#define DIMS     64
#define NCODES   1024
#define DECAY    0.99f
#define EPSF     1e-5f
#define BAND     2e-3f    // approx-gap band; eps_approx ~2e-4, 5x margin

// d_out layout (float32 elements)
#define OFF_ZQ    0
#define OFF_IDX   8388608
#define OFF_LOSS  8519680
#define OFF_PERP  8519681
#define OFF_EMB   8519682
#define OFF_ECS   8585218
#define OFF_EMAW  8586242

typedef unsigned int uint;
typedef short bf16x8 __attribute__((ext_vector_type(8)));
typedef float f32x4  __attribute__((ext_vector_type(4)));

__device__ __forceinline__ float atomic_add_f32(float* p, float v) {
  return __hip_atomic_fetch_add(p, v, __ATOMIC_RELAXED, __HIP_MEMORY_SCOPE_AGENT);
}

__device__ __forceinline__ unsigned short bf16_rne(float f) {
  uint u = __float_as_uint(f);
  uint r = u + 0x7fffu + ((u >> 16) & 1u);
  return (unsigned short)(r >> 16);
}
__device__ __forceinline__ float bf16_f32(unsigned short h) {
  return __uint_as_float(((uint)h) << 16);
}

// numpy pairwise_sum base case (n=64): 8 strided accumulators, tree combine.
__device__ __forceinline__ float np_pairwise64_sq(const float* v) {
#pragma clang fp contract(off)
  float r[8];
#pragma unroll
  for (int j = 0; j < 8; ++j) r[j] = v[j] * v[j];
#pragma unroll
  for (int i = 8; i < 64; i += 8)
#pragma unroll
    for (int j = 0; j < 8; ++j) r[j] += v[i + j] * v[i + j];
  return ((r[0] + r[1]) + (r[2] + r[3])) + ((r[4] + r[5]) + (r[6] + r[7]));
}

// ---------------- K0m: merged init + pack (grid 64) ------------------------
__global__ __launch_bounds__(256) void k0m(const float* __restrict__ emb,
                                           float* __restrict__ ee,
                                           uint* __restrict__ cluster,
                                           uint* __restrict__ cnt,
                                           bf16x8* __restrict__ bsplit,
                                           float* __restrict__ dw) {
  int T = blockIdx.x;
  int t = threadIdx.x;
  int gid = T * 256 + t;               // 16384 threads
  for (int i = gid; i < NCODES * DIMS; i += 16384) dw[i] = 0.0f;

  int l = t & 63;
  int slot = t >> 6;                   // 0..3 = (ktile<<1)|split
  int ktile = slot >> 1, split = slot & 1;
  int code = T * 16 + (l & 15);
  int k0 = ktile * 32 + ((l >> 4) << 3);
  const float* ep = emb + (size_t)code * DIMS + k0;
  float4 fa = *(const float4*)ep;
  float4 fb = *(const float4*)(ep + 4);
  float fs[8] = {fa.x, fa.y, fa.z, fa.w, fb.x, fb.y, fb.z, fb.w};
  bf16x8 v;
#pragma unroll
  for (int i = 0; i < 8; ++i) {
    unsigned short h = bf16_rne(fs[i]);
    if (split == 0) v[i] = (short)h;
    else            v[i] = (short)bf16_rne(fs[i] - bf16_f32(h));
  }
  bsplit[(size_t)((T * 2 + ktile) * 2 + split) * 64 + l] = v;

  if (t < 16) {
    int c = T * 16 + t;
    float ev[DIMS];
    const float4* e4 = (const float4*)(emb + (size_t)c * DIMS);
#pragma unroll
    for (int i = 0; i < 16; ++i) {
      float4 w = e4[i];
      ev[4*i] = w.x; ev[4*i+1] = w.y; ev[4*i+2] = w.z; ev[4*i+3] = w.w;
    }
    ee[c] = np_pairwise64_sq(ev);
  } else if (t < 32) {
    cluster[T * 16 + (t - 16)] = 0u;
  }
  if (T == 0 && t == 32) *cnt = 0u;
}

// ---------------- K1: MFMA approx argmin, LDS-staged bsplit ----------------
// Block = 4 waves over 64 rows. Per tile: block stages 4KB of bsplit into LDS
// (thread t -> frag t>>6, lane t&63; conflict-free b128 pattern), tile T+1
// prefetched into registers before compute(T) so L2 latency hides under MFMA
// (round-11 diagnosis: 8192 waves x 256KB = 2GB L2 stream, latency-bound;
// staging cuts to 512MB and shares across the block's 4 waves).
// A-fragments pre-scaled by -2 (exact: pow2 scaling commutes with bf16 RNE);
// C seeded with ee[code] -> s = ee - 2*dot falls out of the MFMA chain.
// Rounding differs slightly from round-10 (allowed: |err| ~2e-4 << BAND, and
// the k2 exact-recheck net is unchanged). Track/reduce/emit verbatim.
__global__ __launch_bounds__(256) void k1_mfma(const float* __restrict__ z,
                                               const bf16x8* __restrict__ bsplit,
                                               const float* __restrict__ ee,
                                               int* __restrict__ idx_out,
                                               float* __restrict__ idx_f_out,
                                               uint* __restrict__ cluster,
                                               uint* __restrict__ cnt,
                                               uint* __restrict__ list) {
  __shared__ bf16x8 btile[4 * 64];     // 4KB tile: frag f, lane l
  __shared__ float  eel[NCODES];       // 4KB
  int t = threadIdx.x;
  int l = t & 63;
  int w = t >> 6;
  int rowbase = blockIdx.x * 64 + w * 16;
  int arow = rowbase + (l & 15);
  int kq = (l >> 4) << 3;              // 0,8,16,24
  int col = l & 15;

  for (int i = t; i < NCODES; i += 256) eel[i] = ee[i];

  // A fragments: z row split into bf16 hi/mid, pre-scaled by -2.
  // bf16_rne(-2x) == -2*bf16_rne(x) (exact pow2 scaling), so the hi/mid
  // decomposition structure is preserved exactly.
  bf16x8 ahi[2], ami[2];
#pragma unroll
  for (int t2 = 0; t2 < 2; ++t2) {
    const float* zp = z + (size_t)arow * DIMS + t2 * 32 + kq;
    float4 fa = *(const float4*)zp;
    float4 fb = *(const float4*)(zp + 4);
    float fs[8] = {fa.x, fa.y, fa.z, fa.w, fb.x, fb.y, fb.z, fb.w};
#pragma unroll
    for (int i = 0; i < 8; ++i) {
      unsigned short h = bf16_rne(fs[i]);
      float m = fs[i] - bf16_f32(h);
      ahi[t2][i] = (short)bf16_rne(-2.0f * fs[i]);  // == -2*hi
      ami[t2][i] = (short)bf16_rne(-2.0f * m);      // == -2*mid
    }
  }

  float best[4]  = {3.4e38f, 3.4e38f, 3.4e38f, 3.4e38f};
  float second[4] = {3.4e38f, 3.4e38f, 3.4e38f, 3.4e38f};
  int   bidx[4] = {0, 0, 0, 0};

  // prefetch tile 0
  bf16x8 vpre = bsplit[(size_t)(0 * 4 + w) * 64 + l];

  for (int T = 0; T < 64; ++T) {
    __syncthreads();                   // prior tile's reads complete
    btile[w * 64 + l] = vpre;
    if (T < 63) vpre = bsplit[(size_t)((T + 1) * 4 + w) * 64 + l];
    __syncthreads();                   // writes visible

    int code = T * 16 + col;
    float eeT = eel[code];
    bf16x8 bhi0 = btile[0 * 64 + l];
    bf16x8 bmi0 = btile[1 * 64 + l];
    bf16x8 bhi1 = btile[2 * 64 + l];
    bf16x8 bmi1 = btile[3 * 64 + l];

    f32x4 acc = {eeT, eeT, eeT, eeT};  // C-seed: s = ee - 2*dot
    acc = __builtin_amdgcn_mfma_f32_16x16x32_bf16(ahi[0], bhi0, acc, 0, 0, 0);
    acc = __builtin_amdgcn_mfma_f32_16x16x32_bf16(ahi[1], bhi1, acc, 0, 0, 0);
    acc = __builtin_amdgcn_mfma_f32_16x16x32_bf16(ahi[0], bmi0, acc, 0, 0, 0);
    acc = __builtin_amdgcn_mfma_f32_16x16x32_bf16(ahi[1], bmi1, acc, 0, 0, 0);
    acc = __builtin_amdgcn_mfma_f32_16x16x32_bf16(ami[0], bhi0, acc, 0, 0, 0);
    acc = __builtin_amdgcn_mfma_f32_16x16x32_bf16(ami[1], bhi1, acc, 0, 0, 0);

#pragma unroll
    for (int j = 0; j < 4; ++j) {
      float s = acc[j];
      bool lt = s < best[j];
      second[j] = lt ? best[j] : fminf(second[j], s);
      best[j]   = lt ? s : best[j];
      bidx[j]   = lt ? code : bidx[j];
    }
  }

  // reduce (best, second, idx) across the 16 lanes sharing l>>4
#pragma unroll
  for (int m = 1; m < 16; m <<= 1) {
#pragma unroll
    for (int j = 0; j < 4; ++j) {
      float ob = __shfl_xor(best[j], m, 64);
      float os = __shfl_xor(second[j], m, 64);
      int   oi = __shfl_xor(bidx[j], m, 64);
      if (ob < best[j]) {
        second[j] = fminf(os, best[j]);
        best[j] = ob; bidx[j] = oi;
      } else if (ob == best[j]) {
        bidx[j] = min(bidx[j], oi);
        second[j] = fminf(second[j], fminf(os, ob));  // dup min -> gap 0
      } else {
        second[j] = fminf(second[j], ob);
      }
    }
  }

  if (col == 0) {
#pragma unroll
    for (int j = 0; j < 4; ++j) {
      int r = rowbase + ((l >> 4) << 2) + j;
      idx_out[r] = bidx[j];
      idx_f_out[r] = (float)bidx[j];
      atomicAdd(&cluster[bidx[j]], 1u);
      if (second[j] - best[j] < BAND) {
        uint p = atomicAdd(cnt, 1u);
        list[p] = (uint)r;
      }
    }
  }
}

// ---------------- K2: exact recheck of near-tie rows (numpy-f32 bit-exact) --
__global__ __launch_bounds__(256) void k2_recheck(const float* __restrict__ z,
                                                  const float* __restrict__ emb,
                                                  const float* __restrict__ ee,
                                                  const uint* __restrict__ cnt,
                                                  const uint* __restrict__ list,
                                                  int* __restrict__ idx_out,
                                                  float* __restrict__ idx_f_out,
                                                  uint* __restrict__ cluster) {
#pragma clang fp contract(off)
  __shared__ float zrow[DIMS];
  __shared__ float rv[256];
  __shared__ int   ri[256];
  int t = threadIdx.x;
  uint n = *cnt;
  for (uint i = blockIdx.x; i < n; i += gridDim.x) {
    uint row = list[i];
    __syncthreads();
    if (t < 16)
      ((float4*)zrow)[t] = ((const float4*)(z + (size_t)row * DIMS))[t];
    __syncthreads();
    float zz = np_pairwise64_sq(zrow);
    float best = 3.4e38f; int bi = 0;
#pragma unroll
    for (int k4 = 0; k4 < 4; ++k4) {
      int c = t * 4 + k4;                      // ascending codes per thread
      const float* e = emb + (size_t)c * DIMS;
      float a = 0.f;
      for (int k = 0; k < DIMS; ++k) a = fmaf(zrow[k], e[k], a);
      float d = fmaf(-2.0f, a, zz + ee[c]);
      if (d < best) { best = d; bi = c; }
    }
    rv[t] = best; ri[t] = bi;
    __syncthreads();
    for (int s = 128; s > 0; s >>= 1) {
      if (t < s) {
        float ov = rv[t + s]; int oi = ri[t + s];
        if (ov < rv[t] || (ov == rv[t] && oi < ri[t])) { rv[t] = ov; ri[t] = oi; }
      }
      __syncthreads();
    }
    if (t == 0) {
      int old = idx_out[row];
      if (ri[0] != old) {
        atomicSub(&cluster[old], 1u);
        atomicAdd(&cluster[ri[0]], 1u);
        idx_out[row] = ri[0];
        idx_f_out[row] = (float)ri[0];
      }
    }
  }
}

// ---------------- KP: fused 1-block serial pass ----------------------------
// prefix(starts/cursor) + ecs + n + csb + perplexity (all only need final
// cluster counts; loss moved to k4b block 0). Was k3b + most of k4a.
__global__ __launch_bounds__(256) void kp(const uint* __restrict__ cluster,
                                          const float* __restrict__ ecs_in,
                                          uint* __restrict__ starts,
                                          uint* __restrict__ cursor,
                                          float* __restrict__ csb,
                                          float* __restrict__ out) {
  __shared__ uint a[256], b[256];
  __shared__ double red[256];
  int t = threadIdx.x;

  // prefix over 4-code chunks
  uint c0 = cluster[t*4+0], c1 = cluster[t*4+1], c2 = cluster[t*4+2], c3 = cluster[t*4+3];
  uint s4 = c0 + c1 + c2 + c3;
  a[t] = s4;
  __syncthreads();
  uint* src = a; uint* dst = b;
  for (int off = 1; off < 256; off <<= 1) {
    dst[t] = src[t] + ((t >= off) ? src[t - off] : 0u);
    __syncthreads();
    uint* tmp = src; src = dst; dst = tmp;
  }
  uint base = (t > 0) ? src[t-1] : 0u;
  uint p0 = base, p1 = p0 + c0, p2 = p1 + c1, p3 = p2 + c2;
  starts[t*4+0] = p0; starts[t*4+1] = p1; starts[t*4+2] = p2; starts[t*4+3] = p3;
  cursor[t*4+0] = p0; cursor[t*4+1] = p1; cursor[t*4+2] = p2; cursor[t*4+3] = p3;
  if (t == 255) starts[NCODES] = src[255];
  __syncthreads();

  // ecs, n, perplexity sums (same op order as the round-11 k4a)
  double nloc = 0.0, aloc = 0.0, bloc = 0.0;
  for (int c = t; c < NCODES; c += 256) {
    float cntf = (float)cluster[c];
    float ne = ecs_in[c] * DECAY + (1.0f - DECAY) * cntf;
    out[OFF_ECS + c] = ne;
    nloc += (double)ne;
    double p = (double)cntf / (double)N_ROWS;
    double pc = p < 1e-10 ? 1e-10 : p;
    bloc += pc;
    aloc += pc * log(pc);
  }

  red[t] = nloc; __syncthreads();
  for (int s = 128; s > 0; s >>= 1) { if (t < s) red[t] += red[t + s]; __syncthreads(); }
  double n = red[0]; __syncthreads();

  red[t] = bloc; __syncthreads();
  for (int s = 128; s > 0; s >>= 1) { if (t < s) red[t] += red[t + s]; __syncthreads(); }
  double B = red[0]; __syncthreads();

  red[t] = aloc; __syncthreads();
  for (int s = 128; s > 0; s >>= 1) { if (t < s) red[t] += red[t + s]; __syncthreads(); }
  double A = red[0]; __syncthreads();

  if (t == 0) {
    double ent = -(A / B - log(B));
    out[OFF_PERP] = (float)exp(ent);
  }

  float nf = (float)n;
  for (int c = t; c < NCODES; c += 256) {
    float ne = out[OFF_ECS + c];
    float cs = ((ne + EPSF) / (nf + (float)NCODES * EPSF)) * nf;
    csb[c] = cs < 0.01f ? 0.01f : cs;
  }
}

// ---------------- K3c: scatter row ids + codes into sorted positions -------
__global__ __launch_bounds__(256) void k3c_scatter(const int* __restrict__ idx,
                                                   uint* __restrict__ cursor,
                                                   uint* __restrict__ rowids,
                                                   int* __restrict__ codes) {
  int row = blockIdx.x * 256 + threadIdx.x;
  int code = idx[row];
  uint pos = atomicAdd(&cursor[code], 1u);
  rowids[pos] = (uint)row;
  codes[pos] = code;
}

// ---------------- K3d: POSITION-balanced fused pass: zq + loss + dw --------
__global__ __launch_bounds__(256) void k3d_fused(const float* __restrict__ z,
                                                 const float* __restrict__ emb,
                                                 const uint* __restrict__ rowids,
                                                 const int* __restrict__ codes,
                                                 float* __restrict__ out_zq,
                                                 float* __restrict__ dw,
                                                 double* __restrict__ sqpart) {
  __shared__ double accd[4];
  int lane = threadIdx.x & 63, w = threadIdx.x >> 6;
  int base = blockIdx.x * 128 + w * 32;

  int cur = codes[base];                      // wave-uniform
  float acc = 0.f;
  double ds = 0.0;
  for (int i = 0; i < 32; ++i) {
    int p = base + i;
    uint r = rowids[p];                       // wave-uniform s_load
    int c = codes[p];                         // wave-uniform s_load
    if (c != cur) {                           // uniform branch
      atomic_add_f32(&dw[cur * DIMS + lane], acc);
      acc = 0.f; cur = c;
    }
    float zv = z[(size_t)r * DIMS + lane];    // 256B coalesced
    float ev = emb[c * DIMS + lane];          // L1/L2-hot
    float d = ev - zv;
    float o = zv + d;                         // z_q_st, op-for-op as before
    out_zq[(size_t)r * DIMS + lane] = o;
    acc += zv;
    ds += (double)(d * d);
  }
  atomic_add_f32(&dw[cur * DIMS + lane], acc);

#pragma unroll
  for (int o2 = 32; o2 > 0; o2 >>= 1) ds += __shfl_down(ds, o2, 64);
  if (lane == 0) accd[w] = ds;
  __syncthreads();
  if (threadIdx.x == 0)
    sqpart[blockIdx.x] = (accd[0] + accd[1]) + (accd[2] + accd[3]);
}

// ---------------- K4b: parallel finalize: ema_w + embedding + loss ---------
__global__ __launch_bounds__(256) void k4b_emb(const float* __restrict__ emaw_in,
                                               const float* __restrict__ dw,
                                               const float* __restrict__ csb,
                                               const double* __restrict__ sqpart,
                                               float* __restrict__ out) {
  int i = blockIdx.x * 256 + threadIdx.x;
  int c = i >> 6;
  float nw = emaw_in[i] * DECAY + (1.0f - DECAY) * dw[i];
  out[OFF_EMAW + i] = nw;
  out[OFF_EMB + i] = nw / csb[c];

  if (blockIdx.x == 0) {                      // block-uniform branch: loss
    __shared__ double red[256];
    int t = threadIdx.x;
    double sloc = 0.0;
    for (int k = t; k < 1024; k += 256) sloc += sqpart[k];
    red[t] = sloc; __syncthreads();
    for (int s = 128; s > 0; s >>= 1) { if (t < s) red[t] += red[t + s]; __syncthreads(); }
    if (t == 0) {
      double M = red[0] / (double)((size_t)N_ROWS * DIMS);
      out[OFF_LOSS] = (float)(1.5 * M);       // 0.5*commitment + codebook
    }
  }
}

// ---------------- host ----------------
extern "C" void kernel_launch(void* const* d_in, const int* in_sizes, int n_in,
                              void* d_out, int out_size, void* d_ws, size_t ws_size,
                              hipStream_t stream) {
  const float* z    = (const float*)d_in[0];
  const float* emb  = (const float*)d_in[1];
  const float* ecs  = (const float*)d_in[2];
  const float* emaw = (const float*)d_in[3];
  float* out = (float*)d_out;

  char* ws = (char*)d_ws;
  uint*   cnt    = (uint*)   (ws + 0);          // 16 B
  int*    idxw   = (int*)    (ws + 16);         // 512 KB
  uint*   clus   = (uint*)   (ws + 524304);     // 4 KB
  float*  dw     = (float*)  (ws + 528416);     // 256 KB
  float*  ee     = (float*)  (ws + 790560);     // 4 KB
  float*  csb    = (float*)  (ws + 794656);     // 4 KB
  uint*   starts = (uint*)   (ws + 798752);     // 8 KB
  uint*   cursor = (uint*)   (ws + 806944);     // 4 KB
  uint*   rowids = (uint*)   (ws + 811040);     // 512 KB
  bf16x8* bsplit = (bf16x8*) (ws + 1335328);    // 256 KB
  uint*   rlist  = (uint*)   (ws + 1597472);    // 512 KB
  // sqpart overlaps rlist: rlist dead after k2; sqpart written in k3d.
  double* sqpart = (double*) (ws + 1597472);    // 8 KB (within rlist region)
  int*    codes  = (int*)    (ws + 2121760);    // 512 KB

  k0m<<<64, 256, 0, stream>>>(emb, ee, clus, cnt, bsplit, dw);
  k1_mfma<<<N_ROWS / 64, 256, 0, stream>>>(z, bsplit, ee, idxw, out + OFF_IDX,
                                           clus, cnt, rlist);
  k2_recheck<<<1024, 256, 0, stream>>>(z, emb, ee, cnt, rlist, idxw,
                                       out + OFF_IDX, clus);
  kp<<<1, 256, 0, stream>>>(clus, ecs, starts, cursor, csb, out);
  k3c_scatter<<<N_ROWS / 256, 256, 0, stream>>>(idxw, cursor, rowids, codes);
  k3d_fused<<<N_ROWS / 128, 256, 0, stream>>>(z, emb, rowids, codes,
                                              out + OFF_ZQ, dw, sqpart);
  k4b_emb<<<256, 256, 0, stream>>>(emaw, dw, csb, sqpart, out);
}

// Round 13
// 191.270 us; speedup vs baseline: 2.7050x; 1.0215x over previous
//
#include <hip/hip_runtime.h>
#include <hip/hip_bf16.h>
#include <math.h>

#define N_ROWS   131072   // 8*16384
#define DIMS     64
#define NCODES   1024
#define DECAY    0.99f
#define EPSF     1e-5f
#define BAND     2e-3f    // approx-gap band; eps_approx ~2e-4, 5x margin

// d_out layout (float32 elements)
#define OFF_ZQ    0
#define OFF_IDX   8388608
#define OFF_LOSS  8519680
#define OFF_PERP  8519681
#define OFF_EMB   8519682
#define OFF_ECS   8585218
#define OFF_EMAW  8586242

typedef unsigned int uint;
typedef short bf16x8 __attribute__((ext_vector_type(8)));
typedef float f32x4  __attribute__((ext_vector_type(4)));

__device__ __forceinline__ float atomic_add_f32(float* p, float v) {
  return __hip_atomic_fetch_add(p, v, __ATOMIC_RELAXED, __HIP_MEMORY_SCOPE_AGENT);
}

__device__ __forceinline__ unsigned short bf16_rne(float f) {
  uint u = __float_as_uint(f);
  uint r = u + 0x7fffu + ((u >> 16) & 1u);
  return (unsigned short)(r >> 16);
}
__device__ __forceinline__ float bf16_f32(unsigned short h) {
  return __uint_as_float(((uint)h) << 16);
}

// numpy pairwise_sum base case (n=64): 8 strided accumulators, tree combine.
__device__ __forceinline__ float np_pairwise64_sq(const float* v) {
#pragma clang fp contract(off)
  float r[8];
#pragma unroll
  for (int j = 0; j < 8; ++j) r[j] = v[j] * v[j];
#pragma unroll
  for (int i = 8; i < 64; i += 8)
#pragma unroll
    for (int j = 0; j < 8; ++j) r[j] += v[i + j] * v[i + j];
  return ((r[0] + r[1]) + (r[2] + r[3])) + ((r[4] + r[5]) + (r[6] + r[7]));
}

// ---------------- K0m: merged init + pack (grid 64) ------------------------
__global__ __launch_bounds__(256) void k0m(const float* __restrict__ emb,
                                           float* __restrict__ ee,
                                           uint* __restrict__ cluster,
                                           uint* __restrict__ cnt,
                                           bf16x8* __restrict__ bsplit,
                                           float* __restrict__ dw) {
  int T = blockIdx.x;
  int t = threadIdx.x;
  int gid = T * 256 + t;               // 16384 threads
  for (int i = gid; i < NCODES * DIMS; i += 16384) dw[i] = 0.0f;

  int l = t & 63;
  int slot = t >> 6;                   // 0..3 = (ktile<<1)|split
  int ktile = slot >> 1, split = slot & 1;
  int code = T * 16 + (l & 15);
  int k0 = ktile * 32 + ((l >> 4) << 3);
  const float* ep = emb + (size_t)code * DIMS + k0;
  float4 fa = *(const float4*)ep;
  float4 fb = *(const float4*)(ep + 4);
  float fs[8] = {fa.x, fa.y, fa.z, fa.w, fb.x, fb.y, fb.z, fb.w};
  bf16x8 v;
#pragma unroll
  for (int i = 0; i < 8; ++i) {
    unsigned short h = bf16_rne(fs[i]);
    if (split == 0) v[i] = (short)h;
    else            v[i] = (short)bf16_rne(fs[i] - bf16_f32(h));
  }
  bsplit[(size_t)((T * 2 + ktile) * 2 + split) * 64 + l] = v;

  if (t < 16) {
    int c = T * 16 + t;
    float ev[DIMS];
    const float4* e4 = (const float4*)(emb + (size_t)c * DIMS);
#pragma unroll
    for (int i = 0; i < 16; ++i) {
      float4 w = e4[i];
      ev[4*i] = w.x; ev[4*i+1] = w.y; ev[4*i+2] = w.z; ev[4*i+3] = w.w;
    }
    ee[c] = np_pairwise64_sq(ev);
  } else if (t < 32) {
    cluster[T * 16 + (t - 16)] = 0u;
  }
  if (T == 0 && t == 32) *cnt = 0u;
}

// ---------------- K1: MFMA argmin + fused zq/loss epilogue -----------------
// Round-12 fix: prefetch is issued AFTER the second barrier (the old order
// put it between the barriers, and __syncthreads' vmcnt(0) drained it every
// tile -> ~200cy exposed L2 latency/tile). 2 tiles per barrier pair.
// Epilogue (phase 2): block re-reads its 64 z rows (L2-hot), gathers
// emb[winner] (16-lane-coalesced 256B), writes zq in-order, accumulates f64
// loss partial -> sqpart[block] (k3d no longer touches zq/loss/emb).
// k2 patches zq/loss/cluster for rows whose index the exact recheck changes.
__global__ __launch_bounds__(256) void k1_mfma(const float* __restrict__ z,
                                               const float* __restrict__ emb,
                                               const bf16x8* __restrict__ bsplit,
                                               const float* __restrict__ ee,
                                               int* __restrict__ idx_out,
                                               float* __restrict__ idx_f_out,
                                               float* __restrict__ out_zq,
                                               double* __restrict__ sqpart,
                                               uint* __restrict__ cluster,
                                               uint* __restrict__ cnt,
                                               uint* __restrict__ list) {
  __shared__ bf16x8 btile[2][256];     // 8KB: [tile parity][frag*64+lane]
  __shared__ float  eel[NCODES];       // 4KB
  __shared__ int    sidx[64];
  __shared__ double wred[4];
  int t = threadIdx.x;
  int l = t & 63;
  int w = t >> 6;
  int rowbase = blockIdx.x * 64 + w * 16;
  int arow = rowbase + (l & 15);
  int kq = (l >> 4) << 3;              // 0,8,16,24
  int col = l & 15;

  for (int i = t; i < NCODES; i += 256) eel[i] = ee[i];

  // A fragments: z row split into bf16 hi/mid, pre-scaled by -2 (exact).
  bf16x8 ahi[2], ami[2];
#pragma unroll
  for (int t2 = 0; t2 < 2; ++t2) {
    const float* zp = z + (size_t)arow * DIMS + t2 * 32 + kq;
    float4 fa = *(const float4*)zp;
    float4 fb = *(const float4*)(zp + 4);
    float fs[8] = {fa.x, fa.y, fa.z, fa.w, fb.x, fb.y, fb.z, fb.w};
#pragma unroll
    for (int i = 0; i < 8; ++i) {
      unsigned short h = bf16_rne(fs[i]);
      float m = fs[i] - bf16_f32(h);
      ahi[t2][i] = (short)bf16_rne(-2.0f * fs[i]);  // == -2*hi
      ami[t2][i] = (short)bf16_rne(-2.0f * m);      // == -2*mid
    }
  }

  float best[4]  = {3.4e38f, 3.4e38f, 3.4e38f, 3.4e38f};
  float second[4] = {3.4e38f, 3.4e38f, 3.4e38f, 3.4e38f};
  int   bidx[4] = {0, 0, 0, 0};

  // prefetch tiles 0,1 (frag w of each)
  bf16x8 vp0 = bsplit[(size_t)(0 * 4 + w) * 64 + l];
  bf16x8 vp1 = bsplit[(size_t)(1 * 4 + w) * 64 + l];

  for (int T = 0; T < 64; T += 2) {
    __syncthreads();                   // prior reads done; prefetch landed
    btile[0][w * 64 + l] = vp0;
    btile[1][w * 64 + l] = vp1;
    __syncthreads();                   // stores visible
    if (T + 2 < 64) {                  // issue NEXT prefetch *after* barrier:
      vp0 = bsplit[(size_t)((T + 2) * 4 + w) * 64 + l];  // in flight during
      vp1 = bsplit[(size_t)((T + 3) * 4 + w) * 64 + l];  // compute below
    }

#pragma unroll
    for (int u = 0; u < 2; ++u) {
      int code = (T + u) * 16 + col;
      float eeT = eel[code];
      bf16x8 bhi0 = btile[u][0 * 64 + l];
      bf16x8 bmi0 = btile[u][1 * 64 + l];
      bf16x8 bhi1 = btile[u][2 * 64 + l];
      bf16x8 bmi1 = btile[u][3 * 64 + l];

      f32x4 acc = {eeT, eeT, eeT, eeT};  // C-seed: s = ee - 2*dot
      acc = __builtin_amdgcn_mfma_f32_16x16x32_bf16(ahi[0], bhi0, acc, 0, 0, 0);
      acc = __builtin_amdgcn_mfma_f32_16x16x32_bf16(ahi[1], bhi1, acc, 0, 0, 0);
      acc = __builtin_amdgcn_mfma_f32_16x16x32_bf16(ahi[0], bmi0, acc, 0, 0, 0);
      acc = __builtin_amdgcn_mfma_f32_16x16x32_bf16(ahi[1], bmi1, acc, 0, 0, 0);
      acc = __builtin_amdgcn_mfma_f32_16x16x32_bf16(ami[0], bhi0, acc, 0, 0, 0);
      acc = __builtin_amdgcn_mfma_f32_16x16x32_bf16(ami[1], bhi1, acc, 0, 0, 0);

#pragma unroll
      for (int j = 0; j < 4; ++j) {
        float s = acc[j];
        bool lt = s < best[j];
        second[j] = lt ? best[j] : fminf(second[j], s);
        best[j]   = lt ? s : best[j];
        bidx[j]   = lt ? code : bidx[j];
      }
    }
  }

  // reduce (best, second, idx) across the 16 lanes sharing l>>4
#pragma unroll
  for (int m = 1; m < 16; m <<= 1) {
#pragma unroll
    for (int j = 0; j < 4; ++j) {
      float ob = __shfl_xor(best[j], m, 64);
      float os = __shfl_xor(second[j], m, 64);
      int   oi = __shfl_xor(bidx[j], m, 64);
      if (ob < best[j]) {
        second[j] = fminf(os, best[j]);
        best[j] = ob; bidx[j] = oi;
      } else if (ob == best[j]) {
        bidx[j] = min(bidx[j], oi);
        second[j] = fminf(second[j], fminf(os, ob));  // dup min -> gap 0
      } else {
        second[j] = fminf(second[j], ob);
      }
    }
  }

  if (col == 0) {
#pragma unroll
    for (int j = 0; j < 4; ++j) {
      int lrow = w * 16 + ((l >> 4) << 2) + j;
      int r = blockIdx.x * 64 + lrow;
      sidx[lrow] = bidx[j];
      idx_out[r] = bidx[j];
      idx_f_out[r] = (float)bidx[j];
      atomicAdd(&cluster[bidx[j]], 1u);
      if (second[j] - best[j] < BAND) {
        uint p = atomicAdd(cnt, 1u);
        list[p] = (uint)r;
      }
    }
  }
  __syncthreads();

  // phase 2: zq write (in-order, coalesced) + f64 loss partial
  double ds = 0.0;
  const float4* z4 = (const float4*)z;
  const float4* e4 = (const float4*)emb;
  float4* zq4 = (float4*)out_zq;
  int blockrow = blockIdx.x * 64;
#pragma unroll
  for (int p = 0; p < 4; ++p) {
    int f = t + p * 256;               // 1024 float4s = 64 rows x 16
    int lrow = f >> 4, d4 = f & 15;
    int code = sidx[lrow];
    float4 zv = z4[(size_t)(blockrow + lrow) * 16 + d4];
    float4 ev = e4[code * 16 + d4];
    float dx = ev.x - zv.x, dy = ev.y - zv.y, dz = ev.z - zv.z, dw_ = ev.w - zv.w;
    float4 o;
    o.x = zv.x + dx; o.y = zv.y + dy; o.z = zv.z + dz; o.w = zv.w + dw_;
    zq4[(size_t)(blockrow + lrow) * 16 + d4] = o;
    float ss = dx * dx + dy * dy + dz * dz + dw_ * dw_;
    ds += (double)ss;
  }
#pragma unroll
  for (int o2 = 32; o2 > 0; o2 >>= 1) ds += __shfl_down(ds, o2, 64);
  if (l == 0) wred[w] = ds;
  __syncthreads();
  if (t == 0) sqpart[blockIdx.x] = (wred[0] + wred[1]) + (wred[2] + wred[3]);
}

// ---------------- K2: exact recheck of near-tie rows (numpy-f32 bit-exact) --
// Patches idx/cluster AND zq/loss for rows whose index changes; per-block
// f64 loss correction -> corr[blockIdx] (plain store, summed in k4b).
__global__ __launch_bounds__(256) void k2_recheck(const float* __restrict__ z,
                                                  const float* __restrict__ emb,
                                                  const float* __restrict__ ee,
                                                  const uint* __restrict__ cnt,
                                                  const uint* __restrict__ list,
                                                  int* __restrict__ idx_out,
                                                  float* __restrict__ idx_f_out,
                                                  float* __restrict__ out_zq,
                                                  uint* __restrict__ cluster,
                                                  double* __restrict__ corr) {
#pragma clang fp contract(off)
  __shared__ float zrow[DIMS];
  __shared__ float rv[256];
  __shared__ int   ri[256];
  __shared__ int   schg, sold, snew;
  int t = threadIdx.x;
  uint n = *cnt;
  double corrAcc = 0.0;
  const float4* e4 = (const float4*)emb;
  float4* zq4 = (float4*)out_zq;

  for (uint i = blockIdx.x; i < n; i += gridDim.x) {
    uint row = list[i];
    __syncthreads();
    if (t < 16)
      ((float4*)zrow)[t] = ((const float4*)(z + (size_t)row * DIMS))[t];
    __syncthreads();
    float zz = np_pairwise64_sq(zrow);
    float best = 3.4e38f; int bi = 0;
#pragma unroll
    for (int k4 = 0; k4 < 4; ++k4) {
      int c = t * 4 + k4;                      // ascending codes per thread
      const float* e = emb + (size_t)c * DIMS;
      float a = 0.f;
      for (int k = 0; k < DIMS; ++k) a = fmaf(zrow[k], e[k], a);
      float d = fmaf(-2.0f, a, zz + ee[c]);
      if (d < best) { best = d; bi = c; }
    }
    rv[t] = best; ri[t] = bi;
    __syncthreads();
    for (int s = 128; s > 0; s >>= 1) {
      if (t < s) {
        float ov = rv[t + s]; int oi = ri[t + s];
        if (ov < rv[t] || (ov == rv[t] && oi < ri[t])) { rv[t] = ov; ri[t] = oi; }
      }
      __syncthreads();
    }
    if (t == 0) {
      int old = idx_out[row];
      if (ri[0] != old) {
        atomicSub(&cluster[old], 1u);
        atomicAdd(&cluster[ri[0]], 1u);
        idx_out[row] = ri[0];
        idx_f_out[row] = (float)ri[0];
        schg = 1; sold = old; snew = ri[0];
      } else {
        schg = 0;
      }
    }
    __syncthreads();
    if (schg && t < 16) {
      float4 zv = make_float4(zrow[t*4], zrow[t*4+1], zrow[t*4+2], zrow[t*4+3]);
      float4 en = e4[snew * 16 + t];
      float4 eo = e4[sold * 16 + t];
      float dxn = en.x - zv.x, dyn = en.y - zv.y, dzn = en.z - zv.z, dwn = en.w - zv.w;
      float4 o;
      o.x = zv.x + dxn; o.y = zv.y + dyn; o.z = zv.z + dzn; o.w = zv.w + dwn;
      zq4[(size_t)row * 16 + t] = o;
      float ssn = dxn * dxn + dyn * dyn + dzn * dzn + dwn * dwn;
      float dxo = eo.x - zv.x, dyo = eo.y - zv.y, dzo = eo.z - zv.z, dwo = eo.w - zv.w;
      float sso = dxo * dxo + dyo * dyo + dzo * dzo + dwo * dwo;
      double cl = (double)ssn - (double)sso;
      cl += __shfl_xor(cl, 1, 64);
      cl += __shfl_xor(cl, 2, 64);
      cl += __shfl_xor(cl, 4, 64);
      cl += __shfl_xor(cl, 8, 64);
      if (t == 0) corrAcc += cl;
    }
  }
  if (t == 0) corr[blockIdx.x] = corrAcc;
}

// ---------------- KP: fused 1-block serial pass ----------------------------
__global__ __launch_bounds__(256) void kp(const uint* __restrict__ cluster,
                                          const float* __restrict__ ecs_in,
                                          uint* __restrict__ starts,
                                          uint* __restrict__ cursor,
                                          float* __restrict__ csb,
                                          float* __restrict__ out) {
  __shared__ uint a[256], b[256];
  __shared__ double red[256];
  int t = threadIdx.x;

  uint c0 = cluster[t*4+0], c1 = cluster[t*4+1], c2 = cluster[t*4+2], c3 = cluster[t*4+3];
  uint s4 = c0 + c1 + c2 + c3;
  a[t] = s4;
  __syncthreads();
  uint* src = a; uint* dst = b;
  for (int off = 1; off < 256; off <<= 1) {
    dst[t] = src[t] + ((t >= off) ? src[t - off] : 0u);
    __syncthreads();
    uint* tmp = src; src = dst; dst = tmp;
  }
  uint base = (t > 0) ? src[t-1] : 0u;
  uint p0 = base, p1 = p0 + c0, p2 = p1 + c1, p3 = p2 + c2;
  starts[t*4+0] = p0; starts[t*4+1] = p1; starts[t*4+2] = p2; starts[t*4+3] = p3;
  cursor[t*4+0] = p0; cursor[t*4+1] = p1; cursor[t*4+2] = p2; cursor[t*4+3] = p3;
  if (t == 255) starts[NCODES] = src[255];
  __syncthreads();

  double nloc = 0.0, aloc = 0.0, bloc = 0.0;
  for (int c = t; c < NCODES; c += 256) {
    float cntf = (float)cluster[c];
    float ne = ecs_in[c] * DECAY + (1.0f - DECAY) * cntf;
    out[OFF_ECS + c] = ne;
    nloc += (double)ne;
    double p = (double)cntf / (double)N_ROWS;
    double pc = p < 1e-10 ? 1e-10 : p;
    bloc += pc;
    aloc += pc * log(pc);
  }

  red[t] = nloc; __syncthreads();
  for (int s = 128; s > 0; s >>= 1) { if (t < s) red[t] += red[t + s]; __syncthreads(); }
  double n = red[0]; __syncthreads();

  red[t] = bloc; __syncthreads();
  for (int s = 128; s > 0; s >>= 1) { if (t < s) red[t] += red[t + s]; __syncthreads(); }
  double B = red[0]; __syncthreads();

  red[t] = aloc; __syncthreads();
  for (int s = 128; s > 0; s >>= 1) { if (t < s) red[t] += red[t + s]; __syncthreads(); }
  double A = red[0]; __syncthreads();

  if (t == 0) {
    double ent = -(A / B - log(B));
    out[OFF_PERP] = (float)exp(ent);
  }

  float nf = (float)n;
  for (int c = t; c < NCODES; c += 256) {
    float ne = out[OFF_ECS + c];
    float cs = ((ne + EPSF) / (nf + (float)NCODES * EPSF)) * nf;
    csb[c] = cs < 0.01f ? 0.01f : cs;
  }
}

// ---------------- K3c: scatter row ids + codes into sorted positions -------
__global__ __launch_bounds__(256) void k3c_scatter(const int* __restrict__ idx,
                                                   uint* __restrict__ cursor,
                                                   uint* __restrict__ rowids,
                                                   int* __restrict__ codes) {
  int row = blockIdx.x * 256 + threadIdx.x;
  int code = idx[row];
  uint pos = atomicAdd(&cursor[code], 1u);
  rowids[pos] = (uint)row;
  codes[pos] = code;
}

// ---------------- K3d: POSITION-balanced dw-only pass ----------------------
// zq/loss moved into k1; this now only run-length-sums z into dw.
__global__ __launch_bounds__(256) void k3d_dw(const float* __restrict__ z,
                                              const uint* __restrict__ rowids,
                                              const int* __restrict__ codes,
                                              float* __restrict__ dw) {
  int lane = threadIdx.x & 63, w = threadIdx.x >> 6;
  int base = blockIdx.x * 128 + w * 32;

  int cur = codes[base];                      // wave-uniform
  float acc = 0.f;
  for (int i = 0; i < 32; ++i) {
    int p = base + i;
    uint r = rowids[p];                       // wave-uniform s_load
    int c = codes[p];                         // wave-uniform s_load
    if (c != cur) {                           // uniform branch
      atomic_add_f32(&dw[cur * DIMS + lane], acc);
      acc = 0.f; cur = c;
    }
    acc += z[(size_t)r * DIMS + lane];        // 256B coalesced
  }
  atomic_add_f32(&dw[cur * DIMS + lane], acc);
}

// ---------------- K4b: parallel finalize: ema_w + embedding + loss ---------
__global__ __launch_bounds__(256) void k4b_emb(const float* __restrict__ emaw_in,
                                               const float* __restrict__ dw,
                                               const float* __restrict__ csb,
                                               const double* __restrict__ sqpart,
                                               const double* __restrict__ corr,
                                               float* __restrict__ out) {
  int i = blockIdx.x * 256 + threadIdx.x;
  int c = i >> 6;
  float nw = emaw_in[i] * DECAY + (1.0f - DECAY) * dw[i];
  out[OFF_EMAW + i] = nw;
  out[OFF_EMB + i] = nw / csb[c];

  if (blockIdx.x == 0) {                      // block-uniform branch: loss
    __shared__ double red[256];
    int t = threadIdx.x;
    double sloc = 0.0;
    for (int k = t; k < 2048; k += 256) sloc += sqpart[k];
    for (int k = t; k < 1024; k += 256) sloc += corr[k];
    red[t] = sloc; __syncthreads();
    for (int s = 128; s > 0; s >>= 1) { if (t < s) red[t] += red[t + s]; __syncthreads(); }
    if (t == 0) {
      double M = red[0] / (double)((size_t)N_ROWS * DIMS);
      out[OFF_LOSS] = (float)(1.5 * M);       // 0.5*commitment + codebook
    }
  }
}

// ---------------- host ----------------
extern "C" void kernel_launch(void* const* d_in, const int* in_sizes, int n_in,
                              void* d_out, int out_size, void* d_ws, size_t ws_size,
                              hipStream_t stream) {
  const float* z    = (const float*)d_in[0];
  const float* emb  = (const float*)d_in[1];
  const float* ecs  = (const float*)d_in[2];
  const float* emaw = (const float*)d_in[3];
  float* out = (float*)d_out;

  char* ws = (char*)d_ws;
  uint*   cnt    = (uint*)   (ws + 0);          // 16 B
  int*    idxw   = (int*)    (ws + 16);         // 512 KB
  uint*   clus   = (uint*)   (ws + 524304);     // 4 KB
  float*  dw     = (float*)  (ws + 528416);     // 256 KB
  float*  ee     = (float*)  (ws + 790560);     // 4 KB
  float*  csb    = (float*)  (ws + 794656);     // 4 KB
  uint*   starts = (uint*)   (ws + 798752);     // 8 KB
  uint*   cursor = (uint*)   (ws + 806944);     // 4 KB
  uint*   rowids = (uint*)   (ws + 811040);     // 512 KB
  bf16x8* bsplit = (bf16x8*) (ws + 1335328);    // 256 KB
  uint*   rlist  = (uint*)   (ws + 1597472);    // 512 KB
  int*    codes  = (int*)    (ws + 2121760);    // 512 KB
  double* sqpart = (double*) (ws + 2646048);    // 16 KB (2048 k1 blocks)
  double* corr   = (double*) (ws + 2662432);    // 8 KB  (1024 k2 blocks)

  k0m<<<64, 256, 0, stream>>>(emb, ee, clus, cnt, bsplit, dw);
  k1_mfma<<<N_ROWS / 64, 256, 0, stream>>>(z, emb, bsplit, ee, idxw,
                                           out + OFF_IDX, out + OFF_ZQ,
                                           sqpart, clus, cnt, rlist);
  k2_recheck<<<1024, 256, 0, stream>>>(z, emb, ee, cnt, rlist, idxw,
                                       out + OFF_IDX, out + OFF_ZQ, clus, corr);
  kp<<<1, 256, 0, stream>>>(clus, ecs, starts, cursor, csb, out);
  k3c_scatter<<<N_ROWS / 256, 256, 0, stream>>>(idxw, cursor, rowids, codes);
  k3d_dw<<<N_ROWS / 128, 256, 0, stream>>>(z, rowids, codes, dw);
  k4b_emb<<<256, 256, 0, stream>>>(emaw, dw, csb, sqpart, corr, out);
}